// Round 6
// baseline (189.484 us; speedup 1.0000x reference)
//
#include <hip/hip_runtime.h>

// NonLocal (flash attention, d=32) + collapsed ASPP, all MFMA bf16 on gfx950.
// 3 dispatches:
//   k_proj: QKV projections + WzF/bias2 + zmean zero (everything attn needs)
//   k_attn: 512 attention blocks (8-wave K-split, fused merge/Wz/residual/zmean)
//           + 529 aux blocks (z_pad halo zero, Wfrag prep, transposes) that
//           backfill CUs as attention drains
//   k_conv: collapsed 28-tap ASPP conv, 4 waves/block, software-pipelined
// Layout conventions (A: m=lane&15,k=quad*8+j | B: n=lane&15,k=quad*8+j |
//                     D: n=lane&15,m=quad*4+r)
//
// R5 post-mortem: halo-zero used col=c+57 (cols 64..70 = INTERIOR) — a latent
// bug masked in R2-R4 by dispatch ordering + 0xAA poison decoding to ~3e-13
// in bf16. Fusing halo-zero into k_attn made it race with merge writes.
// Fix: c+64 (cols 71..77, the true right halo; disjoint from interior).

typedef __attribute__((ext_vector_type(8))) short bf16x8;
typedef __attribute__((ext_vector_type(4))) short s16x4;
typedef __attribute__((ext_vector_type(4))) float f32x4;

#define MFMA(a, b, c) __builtin_amdgcn_mfma_f32_16x16x32_bf16((a), (b), (c), 0, 0, 0)

#if __has_builtin(__builtin_amdgcn_exp2f)
#define EXP2(x) __builtin_amdgcn_exp2f(x)
#else
#define EXP2(x) exp2f(x)
#endif

__device__ static inline short f2bf(float f) {
  union { float f; unsigned u; } v; v.f = f;
  unsigned r = v.u + 0x7fffu + ((v.u >> 16) & 1u);
  return (short)(r >> 16);
}
__device__ static inline s16x4 pk4(f32x4 v) {
  s16x4 r; r.x = f2bf(v.x); r.y = f2bf(v.y); r.z = f2bf(v.z); r.w = f2bf(v.w);
  return r;
}
// truncating 2xfp32 -> packed bf16x2 dword
__device__ static inline unsigned pk2(float f0, float f1) {
  union { float f; unsigned u; } a, b; a.f = f0; b.f = f1;
  return __builtin_amdgcn_perm(b.u, a.u, 0x07060302u);
}
__device__ static inline f32x4 exp24(f32x4 v) {
  f32x4 r; r.x = EXP2(v.x); r.y = EXP2(v.y); r.z = EXP2(v.z); r.w = EXP2(v.w);
  return r;
}

#define QF_PER_B 131072
#define ZPB      389376
#define LOG2E    1.4426950408889634f

// ================= k_proj: QKV + WzF/bias2 + zmean zero =================
__global__ __launch_bounds__(256) void k_proj(
    const float* __restrict__ x,
    const float* __restrict__ tw, const float* __restrict__ tb,
    const float* __restrict__ pw, const float* __restrict__ pb,
    const float* __restrict__ gw, const float* __restrict__ gb,
    const float* __restrict__ Wz_w, const float* __restrict__ Wz_b,
    const float* __restrict__ bn_g, const float* __restrict__ bn_b,
    unsigned short* __restrict__ thetaB, unsigned short* __restrict__ phiB,
    unsigned short* __restrict__ gB, unsigned short* __restrict__ WzF,
    float* __restrict__ bias2, float* __restrict__ zmean) {
  __shared__ float wl[2048];
  __shared__ float bl[32];
  int blk = blockIdx.x, t = threadIdx.x;
  if (blk < 192) {
    int b = blk & 3, pt = (blk >> 2) & 15, proj = blk >> 6;
    const float* w    = proj == 0 ? tw : (proj == 1 ? pw : gw);
    const float* bias = proj == 0 ? tb : (proj == 1 ? pb : gb);
    for (int i = t; i < 2048; i += 256) wl[i] = w[i];
    if (t < 32) bl[t] = bias[t];
    __syncthreads();
    int pix = pt*256 + t;
    const float* xp = x + b*64*4096 + pix;
    float acc[32];
    #pragma unroll
    for (int ci = 0; ci < 32; ++ci) acc[ci] = bl[ci];
    // chunked loads: force 16 outstanding global loads per batch (MLP)
    for (int c0 = 0; c0 < 64; c0 += 16) {
      float xv[16];
      #pragma unroll
      for (int k = 0; k < 16; ++k) xv[k] = xp[(c0 + k)*4096];
      #pragma unroll
      for (int k = 0; k < 16; ++k)
        #pragma unroll
        for (int ci = 0; ci < 32; ++ci) acc[ci] += wl[ci*64 + c0 + k] * xv[k];
    }
    if (proj == 0) {
      #pragma unroll
      for (int ci = 0; ci < 32; ++ci) acc[ci] *= LOG2E;
    }
    if (proj < 2) {
      unsigned short* base = (proj == 0 ? thetaB : phiB) + b*QF_PER_B
                             + (pix >> 4)*512 + (pix & 15)*8;
      #pragma unroll
      for (int q = 0; q < 4; ++q) {
        bf16x8 v;
        #pragma unroll
        for (int j = 0; j < 8; ++j) v[j] = f2bf(acc[q*8 + j]);
        *(bf16x8*)(base + q*128) = v;
      }
    } else {
      unsigned short* base = gB + b*QF_PER_B + (pix >> 5)*1024
                             + ((pix & 31) >> 3)*128 + (pix & 7);
      #pragma unroll
      for (int ci = 0; ci < 32; ++ci)
        base[(ci >> 4)*512 + (ci & 15)*8] = (unsigned short)f2bf(acc[ci]);
    }
  } else if (blk == 192) {
    int ct = t >> 6, lane = t & 63, quad = lane >> 4, l15 = lane & 15;
    int c = ct * 16 + l15;
    float s = bn_g[c] * rsqrtf(1.f + 1e-5f);
    bf16x8 v;
    #pragma unroll
    for (int j = 0; j < 8; ++j) v[j] = f2bf(s * Wz_w[c * 32 + quad * 8 + j]);
    *(bf16x8*)(WzF + (ct * 64 + lane) * 8) = v;
    if (t < 64) {
      float s2 = bn_g[t] * rsqrtf(1.f + 1e-5f);
      bias2[t] = s2 * Wz_b[t] + bn_b[t];
    }
  } else {
    zmean[t] = 0.f;
  }
}

// ====== k_attn: flash attention + aux (halo zero, Wfrag, transposes) ======
// blk<512: attention (b, qblk), 8 waves, K-split 8, fused merge.
// blk in [512,1012): z_pad halo zero. [1012,1040): Wfrag taps. 1040: transposes.
__global__ __launch_bounds__(512, 4) void k_attn(
    const unsigned short* __restrict__ thetaB, const unsigned short* __restrict__ phiB,
    const unsigned short* __restrict__ gB, const unsigned short* __restrict__ WzF,
    const float* __restrict__ bias2, const float* __restrict__ x,
    unsigned short* __restrict__ z_pad, float* __restrict__ zmean,
    const float* __restrict__ out_w, const float* __restrict__ out_b,
    const float* __restrict__ a1_w, const float* __restrict__ a3_w,
    const float* __restrict__ a5_w, const float* __restrict__ a7_w,
    const float* __restrict__ a1_b, const float* __restrict__ a3_b,
    const float* __restrict__ a5_b, const float* __restrict__ a7_b,
    const float* __restrict__ am_w,
    unsigned short* __restrict__ Wfrag, float* __restrict__ am_wT,
    float* __restrict__ owT0, float* __restrict__ cbias) {
  __shared__ union {
    struct {
      float ypart[8][64][20];
      unsigned short plds[8][1152];
      unsigned short ytr[4][1280];
    } attn;                                   // 69632 B
    struct { float wsm[4096]; float osm[64 * 65]; } prep;  // 33024 B
  } sm;
  int blk = blockIdx.x, tid = threadIdx.x;
  if (blk < 512) {
    int b = blk >> 7, qblk = blk & 127;
    int kh = tid >> 6, lane = tid & 63, quad = lane >> 4, l15 = lane & 15;
    const bf16x8* thB = (const bf16x8*)(thetaB + b*QF_PER_B);
    const bf16x8* phF = (const bf16x8*)(phiB + b*QF_PER_B);
    const bf16x8* gF  = (const bf16x8*)(gB + b*QF_PER_B);
    bf16x8 th0 = thB[(qblk*2 + 0)*64 + lane];
    bf16x8 th1 = thB[(qblk*2 + 1)*64 + lane];
    bf16x8 ones;
    #pragma unroll
    for (int j = 0; j < 8; ++j) ones[j] = (short)0x3F80;
    const f32x4 z4 = {0.f, 0.f, 0.f, 0.f};
    f32x4 acc00 = z4, acc01 = z4, acc10 = z4, acc11 = z4;
    f32x4 accL0 = z4, accL1 = z4;
    unsigned short* pl = &sm.attn.plds[kh][0];
    unsigned short* r0p = pl + l15*36 + quad*4;
    unsigned short* r1p = pl + 576 + l15*36 + quad*4;
    const unsigned short* q0p = pl + l15*36 + quad*8;
    const unsigned short* q1p = pl + 576 + l15*36 + quad*8;
    int kt0 = kh*16;
    int tb0 = kt0*128 + lane;
    bf16x8 pf0 = phF[tb0], pf1 = phF[tb0 + 64];
    bf16x8 gf0 = gF[tb0],  gf1 = gF[tb0 + 64];
    for (int kt = kt0; kt < kt0 + 16; ++kt) {
      bf16x8 cp0 = pf0, cp1 = pf1, cg0 = gf0, cg1 = gf1;
      if (kt + 1 < kt0 + 16) {  // prefetch next iteration's fragments
        int tb = (kt + 1)*128 + lane;
        pf0 = phF[tb]; pf1 = phF[tb + 64];
        gf0 = gF[tb];  gf1 = gF[tb + 64];
      }
      f32x4 s00 = MFMA(cp0, th0, z4);
      f32x4 s10 = MFMA(cp1, th0, z4);
      f32x4 s01 = MFMA(cp0, th1, z4);
      f32x4 s11 = MFMA(cp1, th1, z4);
      f32x4 p00 = exp24(s00), p10 = exp24(s10), p01 = exp24(s01), p11 = exp24(s11);
      uint2 w0; w0.x = pk2(p00.x, p00.y); w0.y = pk2(p00.z, p00.w);
      uint2 w1; w1.x = pk2(p10.x, p10.y); w1.y = pk2(p10.z, p10.w);
      uint2 w2; w2.x = pk2(p01.x, p01.y); w2.y = pk2(p01.z, p01.w);
      uint2 w3; w3.x = pk2(p11.x, p11.y); w3.y = pk2(p11.z, p11.w);
      *(uint2*)(r0p)      = w0;
      *(uint2*)(r0p + 16) = w1;
      *(uint2*)(r1p)      = w2;
      *(uint2*)(r1p + 16) = w3;
      uint2 a0 = *(const uint2*)(q0p);
      uint2 a1 = *(const uint2*)(q0p + 4);
      uint2 b0 = *(const uint2*)(q1p);
      uint2 b1 = *(const uint2*)(q1p + 4);
      union { unsigned u[4]; bf16x8 v; } pb0c, pb1c;
      pb0c.u[0] = a0.x; pb0c.u[1] = a0.y; pb0c.u[2] = a1.x; pb0c.u[3] = a1.y;
      pb1c.u[0] = b0.x; pb1c.u[1] = b0.y; pb1c.u[2] = b1.x; pb1c.u[3] = b1.y;
      acc00 = MFMA(cg0, pb0c.v, acc00);
      acc01 = MFMA(cg1, pb0c.v, acc01);
      acc10 = MFMA(cg0, pb1c.v, acc10);
      acc11 = MFMA(cg1, pb1c.v, acc11);
      accL0 = MFMA(ones, pb0c.v, accL0);
      accL1 = MFMA(ones, pb1c.v, accL1);
    }
    float* yp = &sm.attn.ypart[kh][lane][0];
    *(f32x4*)(yp + 0)  = acc00;
    *(f32x4*)(yp + 4)  = acc01;
    *(f32x4*)(yp + 8)  = acc10;
    *(f32x4*)(yp + 12) = acc11;
    yp[16] = accL0.x; yp[17] = accL1.x;
    __syncthreads();
    if (kh >= 4) return;
    int ct = kh;
    f32x4 a00 = z4, a01 = z4, a10 = z4, a11 = z4;
    float l0 = 0.f, l1 = 0.f;
    #pragma unroll
    for (int k = 0; k < 8; ++k) {
      const float* q = &sm.attn.ypart[k][lane][0];
      a00 += *(const f32x4*)(q + 0);
      a01 += *(const f32x4*)(q + 4);
      a10 += *(const f32x4*)(q + 8);
      a11 += *(const f32x4*)(q + 12);
      l0 += q[16]; l1 += q[17];
    }
    float r0 = 1.f / l0, r1 = 1.f / l1;
    a00 *= r0; a01 *= r0; a10 *= r1; a11 *= r1;
    unsigned short* yl = &sm.attn.ytr[ct][0];
    *(s16x4*)(yl + l15*40 + quad*4)             = pk4(a00);
    *(s16x4*)(yl + l15*40 + 16 + quad*4)        = pk4(a01);
    *(s16x4*)(yl + (16 + l15)*40 + quad*4)      = pk4(a10);
    *(s16x4*)(yl + (16 + l15)*40 + 16 + quad*4) = pk4(a11);
    bf16x8 y0 = *(const bf16x8*)(yl + l15*40 + quad*8);
    bf16x8 y1 = *(const bf16x8*)(yl + (16 + l15)*40 + quad*8);
    bf16x8 wf = ((const bf16x8*)WzF)[ct*64 + lane];
    f32x4 zq0 = MFMA(wf, y0, z4);
    f32x4 zq1 = MFMA(wf, y1, z4);
    int c0 = ct*16 + quad*4;
    f32x4 b2 = *(const f32x4*)(bias2 + c0);
    int q0i = qblk * 32;
    const float* xp0 = x + (b*64 + c0)*4096 + q0i + l15;
    f32x4 s0, s1;
    s0.x = zq0.x + b2.x + xp0[0];
    s0.y = zq0.y + b2.y + xp0[4096];
    s0.z = zq0.z + b2.z + xp0[8192];
    s0.w = zq0.w + b2.w + xp0[12288];
    s1.x = zq1.x + b2.x + xp0[16];
    s1.y = zq1.y + b2.y + xp0[4096 + 16];
    s1.z = zq1.z + b2.z + xp0[8192 + 16];
    s1.w = zq1.w + b2.w + xp0[12288 + 16];
    {
      int q = q0i + l15, h = q >> 6, w = q & 63;
      *(s16x4*)(z_pad + b*ZPB + ((h + 7)*78 + (w + 7))*64 + c0) = pk4(s0);
      q = q0i + 16 + l15; h = q >> 6; w = q & 63;
      *(s16x4*)(z_pad + b*ZPB + ((h + 7)*78 + (w + 7))*64 + c0) = pk4(s1);
    }
    f32x4 zs = s0 + s1;
    #pragma unroll
    for (int m = 1; m < 16; m <<= 1) {
      zs.x += __shfl_xor(zs.x, m);
      zs.y += __shfl_xor(zs.y, m);
      zs.z += __shfl_xor(zs.z, m);
      zs.w += __shfl_xor(zs.w, m);
    }
    if (l15 == 0) {
      atomicAdd(zmean + b*64 + c0 + 0, zs.x);
      atomicAdd(zmean + b*64 + c0 + 1, zs.y);
      atomicAdd(zmean + b*64 + c0 + 2, zs.z);
      atomicAdd(zmean + b*64 + c0 + 3, zs.w);
    }
  } else if (blk < 1012) {
    // ---- z_pad halo zero. Halo = rows 0-6 & 71-77 (full width), plus
    // rows 7-70 cols 0-6 & 71-77. Disjoint from merge's interior writes. ----
    int hb = blk - 512;
    int b = hb / 125, loc = hb - b * 125;
    int i = loc * 512 + tid;
    if (i >= 63616) return;
    int px = i >> 5, dw = i & 31;
    int row, col;
    if (px < 1092) {
      int r = px / 78; col = px - r * 78;
      row = (r < 7) ? r : r + 64;
    } else {
      int j = px - 1092;
      int r = j / 14; int c = j - r * 14;
      row = r + 7; col = (c < 7) ? c : c + 64;   // FIXED: right halo = 71..77
    }
    ((unsigned*)z_pad)[b * (ZPB / 2) + (row * 78 + col) * 32 + dw] = 0u;
  } else if (blk < 1040) {
    // ---- Wfrag: combined 28-tap weights (threads 256-511 duplicate: benign) ----
    int tap = blk - 1012;
    const float* w; int goff, kyx = 0, ksq = 9;
    if (tap == 0)      { w = a1_w; goff = 64;  ksq = 1; }
    else if (tap < 10) { w = a3_w; goff = 128; kyx = tap - 1; }
    else if (tap < 19) { w = a5_w; goff = 192; kyx = tap - 10; }
    else               { w = a7_w; goff = 256; kyx = tap - 19; }
    for (int i = tid; i < 4096; i += 512) {
      sm.prep.wsm[i] = w[i * ksq + kyx];
      int d = i >> 6, m = i & 63;
      sm.prep.osm[d * 65 + m] = out_w[d * 320 + goff + m];
    }
    __syncthreads();
    int dt = (tid >> 6) & 3, lane = tid & 63, quad = lane >> 4, l15 = lane & 15;
    int d = dt * 16 + l15;
    float acc[16];
    #pragma unroll
    for (int k = 0; k < 16; ++k) acc[k] = 0.f;
    const float* orow = sm.prep.osm + d * 65;
    int c0 = quad * 8;
    for (int m = 0; m < 64; ++m) {
      float o = orow[m];
      const float* wr = sm.prep.wsm + m * 64 + c0;
      #pragma unroll
      for (int cc = 0; cc < 2; ++cc)
        #pragma unroll
        for (int j = 0; j < 8; ++j)
          acc[cc * 8 + j] += o * wr[cc * 32 + j];
    }
    #pragma unroll
    for (int cc = 0; cc < 2; ++cc) {
      bf16x8 v;
      #pragma unroll
      for (int j = 0; j < 8; ++j) v[j] = f2bf(acc[cc * 8 + j]);
      *(bf16x8*)(Wfrag + (((tap * 4 + dt) * 2 + cc) * 64 + lane) * 8) = v;
    }
  } else {
    // ---- transposed aux weights + constant bias for conv ----
    for (int i = tid; i < 4096; i += 512) {
      int d = i >> 6, c = i & 63;
      am_wT[c * 64 + d] = am_w[i];
      owT0[c * 64 + d] = out_w[d * 320 + c];
    }
    if (tid < 64) {
      float r = out_b[tid];
      const float* ow = out_w + tid * 320;
      for (int m = 0; m < 64; ++m)
        r += ow[64 + m] * a1_b[m] + ow[128 + m] * a3_b[m]
           + ow[192 + m] * a5_b[m] + ow[256 + m] * a7_b[m];
      cbias[tid] = r;
    }
  }
}

// ========== k_conv: 28-tap ASPP conv, 4 waves/block, pipelined ==========
__global__ __launch_bounds__(256, 4) void k_conv(
    const unsigned short* __restrict__ z_pad, const unsigned short* __restrict__ Wfrag,
    const float* __restrict__ zmean, const float* __restrict__ am_wT,
    const float* __restrict__ am_b, const float* __restrict__ owT0,
    const float* __restrict__ cbias, float* __restrict__ out) {
  static constexpr int DYt[28] = {0, -3,-3,-3,0,0,0,3,3,3,
                                     -5,-5,-5,0,0,0,5,5,5,
                                     -7,-7,-7,0,0,0,7,7,7};
  static constexpr int DXt[28] = {0, -3,0,3,-3,0,3,-3,0,3,
                                     -5,0,5,-5,0,5,-5,0,5,
                                     -7,0,7,-7,0,7,-7,0,7};
  int blk = blockIdx.x;                       // b(4) x h(64)
  int b = blk >> 6, h = blk & 63;
  int tid = threadIdx.x;
  int wave = tid >> 6, lane = tid & 63, quad = lane >> 4, l15 = lane & 15;
  int dt2 = wave >> 1, wt2 = wave & 1;
  // ---- inlined c_b (independent; hides under the MFMA loop) ----
  float zml = zmean[b*64 + lane] * (1.f / 4096.f);
  float img = am_b[lane];
  for (int c = 0; c < 64; ++c) img += am_wT[c*64 + lane] * __shfl(zml, c);
  float cbd = cbias[lane];
  for (int dd = 0; dd < 64; ++dd) cbd += owT0[dd*64 + lane] * __shfl(img, dd);
  // ---- main implicit GEMM, software-pipelined over 56 (tap,cc) steps ----
  const unsigned short* zb = z_pad + b*ZPB + ((h + 7)*78 + 7)*64 + quad*8;
  const bf16x8* wfp = (const bf16x8*)Wfrag + lane;
  int d0 = dt2*2 + 0, d1 = dt2*2 + 1;
  const f32x4 z4 = {0.f, 0.f, 0.f, 0.f};
  f32x4 acc00 = z4, acc01 = z4, acc10 = z4, acc11 = z4;
  int col0 = ((wt2*2 + 0)*16 + l15)*64;
  int col1 = ((wt2*2 + 1)*16 + l15)*64;
  bf16x8 zf0 = *(const bf16x8*)(zb + (DYt[0]*78 + DXt[0])*64 + col0);
  bf16x8 zf1 = *(const bf16x8*)(zb + (DYt[0]*78 + DXt[0])*64 + col1);
  #pragma unroll
  for (int idx = 0; idx < 56; ++idx) {
    int tap = idx >> 1, cc = idx & 1;
    bf16x8 c0v = zf0, c1v = zf1;
    if (idx < 55) {
      int ntap = (idx + 1) >> 1, ncc = (idx + 1) & 1;
      const unsigned short* nz = zb + (DYt[ntap]*78 + DXt[ntap])*64 + ncc*32;
      zf0 = *(const bf16x8*)(nz + col0);
      zf1 = *(const bf16x8*)(nz + col1);
    }
    bf16x8 wf0 = wfp[((tap*4 + d0)*2 + cc)*64];
    bf16x8 wf1 = wfp[((tap*4 + d1)*2 + cc)*64];
    acc00 = MFMA(wf0, c0v, acc00);
    acc01 = MFMA(wf0, c1v, acc01);
    acc10 = MFMA(wf1, c0v, acc10);
    acc11 = MFMA(wf1, c1v, acc11);
  }
  int dd0 = d0*16 + quad*4, dd1 = d1*16 + quad*4;
  f32x4 cb0v, cb1v;
  cb0v.x = __shfl(cbd, dd0 + 0); cb0v.y = __shfl(cbd, dd0 + 1);
  cb0v.z = __shfl(cbd, dd0 + 2); cb0v.w = __shfl(cbd, dd0 + 3);
  cb1v.x = __shfl(cbd, dd1 + 0); cb1v.y = __shfl(cbd, dd1 + 1);
  cb1v.z = __shfl(cbd, dd1 + 2); cb1v.w = __shfl(cbd, dd1 + 3);
  acc00 += cb0v; acc01 += cb0v; acc10 += cb1v; acc11 += cb1v;
  float* ob = out + b*262144 + h*64;
  int w0 = (wt2*2 + 0)*16 + l15, w1 = (wt2*2 + 1)*16 + l15;
  ob[(dd0 + 0)*4096 + w0] = acc00.x;
  ob[(dd0 + 1)*4096 + w0] = acc00.y;
  ob[(dd0 + 2)*4096 + w0] = acc00.z;
  ob[(dd0 + 3)*4096 + w0] = acc00.w;
  ob[(dd0 + 0)*4096 + w1] = acc01.x;
  ob[(dd0 + 1)*4096 + w1] = acc01.y;
  ob[(dd0 + 2)*4096 + w1] = acc01.z;
  ob[(dd0 + 3)*4096 + w1] = acc01.w;
  ob[(dd1 + 0)*4096 + w0] = acc10.x;
  ob[(dd1 + 1)*4096 + w0] = acc10.y;
  ob[(dd1 + 2)*4096 + w0] = acc10.z;
  ob[(dd1 + 3)*4096 + w0] = acc10.w;
  ob[(dd1 + 0)*4096 + w1] = acc11.x;
  ob[(dd1 + 1)*4096 + w1] = acc11.y;
  ob[(dd1 + 2)*4096 + w1] = acc11.z;
  ob[(dd1 + 3)*4096 + w1] = acc11.w;
}

extern "C" void kernel_launch(void* const* d_in, const int* in_sizes, int n_in,
                              void* d_out, int out_size, void* d_ws, size_t ws_size,
                              hipStream_t stream) {
  const float* x    = (const float*)d_in[0];
  const float* g_w  = (const float*)d_in[1];
  const float* g_b  = (const float*)d_in[2];
  const float* th_w = (const float*)d_in[3];
  const float* th_b = (const float*)d_in[4];
  const float* ph_w = (const float*)d_in[5];
  const float* ph_b = (const float*)d_in[6];
  const float* Wz_w = (const float*)d_in[7];
  const float* Wz_b = (const float*)d_in[8];
  const float* bn_g = (const float*)d_in[9];
  const float* bn_b = (const float*)d_in[10];
  const float* am_w = (const float*)d_in[11];
  const float* am_b = (const float*)d_in[12];
  const float* a1_w = (const float*)d_in[13];
  const float* a1_b = (const float*)d_in[14];
  const float* a3_w = (const float*)d_in[15];
  const float* a3_b = (const float*)d_in[16];
  const float* a5_w = (const float*)d_in[17];
  const float* a5_b = (const float*)d_in[18];
  const float* a7_w = (const float*)d_in[19];
  const float* a7_b = (const float*)d_in[20];
  const float* out_w = (const float*)d_in[21];
  const float* out_b = (const float*)d_in[22];
  float* out = (float*)d_out;
  char* ws = (char*)d_ws;
  unsigned short* thetaB = (unsigned short*)(ws + 0);
  unsigned short* phiB   = (unsigned short*)(ws + 1048576);
  unsigned short* gB     = (unsigned short*)(ws + 2097152);
  unsigned short* z_pad  = (unsigned short*)(ws + 3145728);
  unsigned short* Wfrag  = (unsigned short*)(ws + 6260736);
  unsigned short* WzF    = (unsigned short*)(ws + 6490112);
  float* zmean           = (float*)(ws + 6494208);
  float* bias2           = (float*)(ws + 6495232);
  float* am_wT           = (float*)(ws + 6495488);
  float* owT0            = (float*)(ws + 6511872);
  float* cbias           = (float*)(ws + 6528256);

  k_proj<<<dim3(194), dim3(256), 0, stream>>>(
      x, th_w, th_b, ph_w, ph_b, g_w, g_b, Wz_w, Wz_b, bn_g, bn_b,
      thetaB, phiB, gB, WzF, bias2, zmean);
  k_attn<<<dim3(1041), dim3(512), 0, stream>>>(
      thetaB, phiB, gB, WzF, bias2, x, z_pad, zmean,
      out_w, out_b, a1_w, a3_w, a5_w, a7_w, a1_b, a3_b, a5_b, a7_b, am_w,
      Wfrag, am_wT, owT0, cbias);
  k_conv<<<dim3(256), dim3(256), 0, stream>>>(z_pad, Wfrag, zmean, am_wT, am_b,
                                              owT0, cbias, out);
}

// Round 7
// 180.701 us; speedup vs baseline: 1.0486x; 1.0486x over previous
//
#include <hip/hip_runtime.h>

// NonLocal (flash attention, d=32) + collapsed ASPP, all MFMA bf16 on gfx950.
// 3 dispatches:
//   k_proj: QKV + WzF/bias2 + zmean zero + aux (halo zero, Wfrag, transposes)
//   k_attn: 512 blocks x 8 waves, K-split 8, in-LDS merge + Wz + residual +
//           zmean atomics. LDS dieted to 38,912 B (>=2 blocks/CU co-residency).
//   k_conv: 28-tap implicit GEMM, depth-4 dual (z+w) register prefetch.
// Layout conventions (A: m=lane&15,k=quad*8+j | B: n=lane&15,k=quad*8+j |
//                     D: n=lane&15,m=quad*4+r)

typedef __attribute__((ext_vector_type(8))) short bf16x8;
typedef __attribute__((ext_vector_type(4))) short s16x4;
typedef __attribute__((ext_vector_type(4))) float f32x4;

#define MFMA(a, b, c) __builtin_amdgcn_mfma_f32_16x16x32_bf16((a), (b), (c), 0, 0, 0)

#if __has_builtin(__builtin_amdgcn_exp2f)
#define EXP2(x) __builtin_amdgcn_exp2f(x)
#else
#define EXP2(x) exp2f(x)
#endif

__device__ static inline short f2bf(float f) {
  union { float f; unsigned u; } v; v.f = f;
  unsigned r = v.u + 0x7fffu + ((v.u >> 16) & 1u);
  return (short)(r >> 16);
}
__device__ static inline s16x4 pk4(f32x4 v) {
  s16x4 r; r.x = f2bf(v.x); r.y = f2bf(v.y); r.z = f2bf(v.z); r.w = f2bf(v.w);
  return r;
}
// truncating 2xfp32 -> packed bf16x2 dword (low16 = f0, high16 = f1)
__device__ static inline unsigned pk2(float f0, float f1) {
  union { float f; unsigned u; } a, b; a.f = f0; b.f = f1;
  return __builtin_amdgcn_perm(b.u, a.u, 0x07060302u);
}
__device__ static inline float unlo(unsigned d) {
  union { unsigned u; float f; } v; v.u = d << 16; return v.f;
}
__device__ static inline float unhi(unsigned d) {
  union { unsigned u; float f; } v; v.u = d & 0xffff0000u; return v.f;
}
__device__ static inline unsigned fasu(float f) {
  union { float f; unsigned u; } v; v.f = f; return v.u;
}
__device__ static inline float uasf(unsigned u) {
  union { unsigned u; float f; } v; v.u = u; return v.f;
}
__device__ static inline f32x4 exp24(f32x4 v) {
  f32x4 r; r.x = EXP2(v.x); r.y = EXP2(v.y); r.z = EXP2(v.z); r.w = EXP2(v.w);
  return r;
}

#define QF_PER_B 131072
#define ZPB      389376
#define LOG2E    1.4426950408889634f

// ====== k_proj: QKV + WzF/bias2/zmean + halo zero + Wfrag + transposes ======
// blocks [0,192): QKV. 192: WzF/bias2/zmean. [193,1189): halo zero.
// [1189,1217): Wfrag taps. 1217: transposes + cbias.
__global__ __launch_bounds__(256) void k_proj(
    const float* __restrict__ x,
    const float* __restrict__ tw, const float* __restrict__ tb,
    const float* __restrict__ pw, const float* __restrict__ pb,
    const float* __restrict__ gw, const float* __restrict__ gb,
    const float* __restrict__ Wz_w, const float* __restrict__ Wz_b,
    const float* __restrict__ bn_g, const float* __restrict__ bn_b,
    const float* __restrict__ out_w, const float* __restrict__ out_b,
    const float* __restrict__ a1_w, const float* __restrict__ a3_w,
    const float* __restrict__ a5_w, const float* __restrict__ a7_w,
    const float* __restrict__ a1_b, const float* __restrict__ a3_b,
    const float* __restrict__ a5_b, const float* __restrict__ a7_b,
    const float* __restrict__ am_w,
    unsigned short* __restrict__ thetaB, unsigned short* __restrict__ phiB,
    unsigned short* __restrict__ gB, unsigned short* __restrict__ WzF,
    float* __restrict__ bias2, float* __restrict__ zmean,
    unsigned* __restrict__ zp, unsigned short* __restrict__ Wfrag,
    float* __restrict__ am_wT, float* __restrict__ owT0,
    float* __restrict__ cbias) {
  __shared__ union {
    struct { float wl[2048]; float bl[32]; } qkv;
    struct { float wsm[4096]; float osm[64 * 65]; } prep;
  } sm;
  int blk = blockIdx.x, t = threadIdx.x;
  if (blk < 192) {
    int b = blk & 3, pt = (blk >> 2) & 15, proj = blk >> 6;
    const float* w    = proj == 0 ? tw : (proj == 1 ? pw : gw);
    const float* bias = proj == 0 ? tb : (proj == 1 ? pb : gb);
    for (int i = t; i < 2048; i += 256) sm.qkv.wl[i] = w[i];
    if (t < 32) sm.qkv.bl[t] = bias[t];
    __syncthreads();
    int pix = pt*256 + t;
    const float* xp = x + b*64*4096 + pix;
    float acc[32];
    #pragma unroll
    for (int ci = 0; ci < 32; ++ci) acc[ci] = sm.qkv.bl[ci];
    for (int c0 = 0; c0 < 64; c0 += 16) {
      float xv[16];
      #pragma unroll
      for (int k = 0; k < 16; ++k) xv[k] = xp[(c0 + k)*4096];
      #pragma unroll
      for (int k = 0; k < 16; ++k)
        #pragma unroll
        for (int ci = 0; ci < 32; ++ci) acc[ci] += sm.qkv.wl[ci*64 + c0 + k] * xv[k];
    }
    if (proj == 0) {
      #pragma unroll
      for (int ci = 0; ci < 32; ++ci) acc[ci] *= LOG2E;
    }
    if (proj < 2) {
      unsigned short* base = (proj == 0 ? thetaB : phiB) + b*QF_PER_B
                             + (pix >> 4)*512 + (pix & 15)*8;
      #pragma unroll
      for (int q = 0; q < 4; ++q) {
        bf16x8 v;
        #pragma unroll
        for (int j = 0; j < 8; ++j) v[j] = f2bf(acc[q*8 + j]);
        *(bf16x8*)(base + q*128) = v;
      }
    } else {
      unsigned short* base = gB + b*QF_PER_B + (pix >> 5)*1024
                             + ((pix & 31) >> 3)*128 + (pix & 7);
      #pragma unroll
      for (int ci = 0; ci < 32; ++ci)
        base[(ci >> 4)*512 + (ci & 15)*8] = (unsigned short)f2bf(acc[ci]);
    }
  } else if (blk == 192) {
    int ct = t >> 6, lane = t & 63, quad = lane >> 4, l15 = lane & 15;
    int c = ct * 16 + l15;
    float s = bn_g[c] * rsqrtf(1.f + 1e-5f);
    bf16x8 v;
    #pragma unroll
    for (int j = 0; j < 8; ++j) v[j] = f2bf(s * Wz_w[c * 32 + quad * 8 + j]);
    *(bf16x8*)(WzF + (ct * 64 + lane) * 8) = v;
    zmean[t] = 0.f;
    if (t < 64) {
      float s2 = bn_g[t] * rsqrtf(1.f + 1e-5f);
      bias2[t] = s2 * Wz_b[t] + bn_b[t];
    }
  } else if (blk < 1189) {
    // z_pad halo zero: rows 0-6 & 71-77 full width; rows 7-70 cols 0-6 & 71-77.
    int hb = blk - 193;
    int b = hb / 249, loc = hb - b * 249;
    int i = loc * 256 + t;
    if (i >= 63616) return;
    int px = i >> 5, dw = i & 31;
    int row, col;
    if (px < 1092) {
      int r = px / 78; col = px - r * 78;
      row = (r < 7) ? r : r + 64;
    } else {
      int j = px - 1092;
      int r = j / 14; int c = j - r * 14;
      row = r + 7; col = (c < 7) ? c : c + 64;   // right halo = 71..77
    }
    zp[b * (ZPB / 2) + (row * 78 + col) * 32 + dw] = 0u;
  } else if (blk < 1217) {
    // Wfrag: combined 28-tap kernels
    int tap = blk - 1189;
    const float* w; int goff, kyx = 0, ksq = 9;
    if (tap == 0)      { w = a1_w; goff = 64;  ksq = 1; }
    else if (tap < 10) { w = a3_w; goff = 128; kyx = tap - 1; }
    else if (tap < 19) { w = a5_w; goff = 192; kyx = tap - 10; }
    else               { w = a7_w; goff = 256; kyx = tap - 19; }
    for (int i = t; i < 4096; i += 256) {
      sm.prep.wsm[i] = w[i * ksq + kyx];
      int d = i >> 6, m = i & 63;
      sm.prep.osm[d * 65 + m] = out_w[d * 320 + goff + m];
    }
    __syncthreads();
    int dt = t >> 6, lane = t & 63, quad = lane >> 4, l15 = lane & 15;
    int d = dt * 16 + l15;
    float acc[16];
    #pragma unroll
    for (int k = 0; k < 16; ++k) acc[k] = 0.f;
    const float* orow = sm.prep.osm + d * 65;
    int c0 = quad * 8;
    for (int m = 0; m < 64; ++m) {
      float o = orow[m];
      const float* wr = sm.prep.wsm + m * 64 + c0;
      #pragma unroll
      for (int cc = 0; cc < 2; ++cc)
        #pragma unroll
        for (int j = 0; j < 8; ++j)
          acc[cc * 8 + j] += o * wr[cc * 32 + j];
    }
    #pragma unroll
    for (int cc = 0; cc < 2; ++cc) {
      bf16x8 v;
      #pragma unroll
      for (int j = 0; j < 8; ++j) v[j] = f2bf(acc[cc * 8 + j]);
      *(bf16x8*)(Wfrag + (((tap * 4 + dt) * 2 + cc) * 64 + lane) * 8) = v;
    }
  } else {
    // transposed aux weights + constant bias for conv
    for (int i = t; i < 4096; i += 256) {
      int d = i >> 6, c = i & 63;
      am_wT[c * 64 + d] = am_w[i];
      owT0[c * 64 + d] = out_w[d * 320 + c];
    }
    if (t < 64) {
      float r = out_b[t];
      const float* ow = out_w + t * 320;
      for (int m = 0; m < 64; ++m)
        r += ow[64 + m] * a1_b[m] + ow[128 + m] * a3_b[m]
           + ow[192 + m] * a5_b[m] + ow[256 + m] * a7_b[m];
      cbias[t] = r;
    }
  }
}

// ====== k_attn: flash attention, K-split=8 in-block, fused merge/Wz/zmean ======
// LDS = ypk (packed bf16 partials, SoA, conflict-free) 20,480 B
//     + plds (transpose buffers; aliased as ytr post-barrier) 18,432 B
//     = 38,912 B  -> >=2 blocks/CU (up to 4).
__global__ __launch_bounds__(512, 4) void k_attn(
    const unsigned short* __restrict__ thetaB, const unsigned short* __restrict__ phiB,
    const unsigned short* __restrict__ gB, const unsigned short* __restrict__ WzF,
    const float* __restrict__ bias2, const float* __restrict__ x,
    unsigned short* __restrict__ z_pad, float* __restrict__ zmean) {
  __shared__ struct {
    unsigned ypk[8][10][64];                 // [wave][dword][lane]: 8 y-bf16x2 + 2 l
    __align__(16) unsigned short plds[8][1152];
  } sm;
  int blk = blockIdx.x;                       // b(4) x qblk(128)
  int b = blk >> 7, qblk = blk & 127;
  int tid = threadIdx.x;
  int kh = tid >> 6, lane = tid & 63, quad = lane >> 4, l15 = lane & 15;
  const bf16x8* thB = (const bf16x8*)(thetaB + b*QF_PER_B);
  const bf16x8* phF = (const bf16x8*)(phiB + b*QF_PER_B);
  const bf16x8* gF  = (const bf16x8*)(gB + b*QF_PER_B);
  bf16x8 th0 = thB[(qblk*2 + 0)*64 + lane];
  bf16x8 th1 = thB[(qblk*2 + 1)*64 + lane];
  bf16x8 ones;
  #pragma unroll
  for (int j = 0; j < 8; ++j) ones[j] = (short)0x3F80;
  const f32x4 z4 = {0.f, 0.f, 0.f, 0.f};
  f32x4 acc00 = z4, acc01 = z4, acc10 = z4, acc11 = z4;
  f32x4 accL0 = z4, accL1 = z4;
  unsigned short* pl = &sm.plds[kh][0];
  unsigned short* r0p = pl + l15*36 + quad*4;
  unsigned short* r1p = pl + 576 + l15*36 + quad*4;
  const unsigned short* q0p = pl + l15*36 + quad*8;
  const unsigned short* q1p = pl + 576 + l15*36 + quad*8;
  int kt0 = kh*16;
  int tb0 = kt0*128 + lane;
  bf16x8 pf0 = phF[tb0], pf1 = phF[tb0 + 64];
  bf16x8 gf0 = gF[tb0],  gf1 = gF[tb0 + 64];
  for (int kt = kt0; kt < kt0 + 16; ++kt) {
    bf16x8 cp0 = pf0, cp1 = pf1, cg0 = gf0, cg1 = gf1;
    if (kt + 1 < kt0 + 16) {  // prefetch next iteration's fragments
      int tb = (kt + 1)*128 + lane;
      pf0 = phF[tb]; pf1 = phF[tb + 64];
      gf0 = gF[tb];  gf1 = gF[tb + 64];
    }
    f32x4 s00 = MFMA(cp0, th0, z4);
    f32x4 s10 = MFMA(cp1, th0, z4);
    f32x4 s01 = MFMA(cp0, th1, z4);
    f32x4 s11 = MFMA(cp1, th1, z4);
    f32x4 p00 = exp24(s00), p10 = exp24(s10), p01 = exp24(s01), p11 = exp24(s11);
    uint2 w0; w0.x = pk2(p00.x, p00.y); w0.y = pk2(p00.z, p00.w);
    uint2 w1; w1.x = pk2(p10.x, p10.y); w1.y = pk2(p10.z, p10.w);
    uint2 w2; w2.x = pk2(p01.x, p01.y); w2.y = pk2(p01.z, p01.w);
    uint2 w3; w3.x = pk2(p11.x, p11.y); w3.y = pk2(p11.z, p11.w);
    *(uint2*)(r0p)      = w0;
    *(uint2*)(r0p + 16) = w1;
    *(uint2*)(r1p)      = w2;
    *(uint2*)(r1p + 16) = w3;
    uint2 a0 = *(const uint2*)(q0p);
    uint2 a1 = *(const uint2*)(q0p + 4);
    uint2 b0 = *(const uint2*)(q1p);
    uint2 b1 = *(const uint2*)(q1p + 4);
    union { unsigned u[4]; bf16x8 v; } pb0c, pb1c;
    pb0c.u[0] = a0.x; pb0c.u[1] = a0.y; pb0c.u[2] = a1.x; pb0c.u[3] = a1.y;
    pb1c.u[0] = b0.x; pb1c.u[1] = b0.y; pb1c.u[2] = b1.x; pb1c.u[3] = b1.y;
    acc00 = MFMA(cg0, pb0c.v, acc00);
    acc01 = MFMA(cg1, pb0c.v, acc01);
    acc10 = MFMA(cg0, pb1c.v, acc10);
    acc11 = MFMA(cg1, pb1c.v, acc11);
    accL0 = MFMA(ones, pb0c.v, accL0);
    accL1 = MFMA(ones, pb1c.v, accL1);
  }
  {
    unsigned* yp = &sm.ypk[kh][0][lane];    // stride 64 dwords between rows
    yp[0*64] = pk2(acc00.x, acc00.y);
    yp[1*64] = pk2(acc00.z, acc00.w);
    yp[2*64] = pk2(acc01.x, acc01.y);
    yp[3*64] = pk2(acc01.z, acc01.w);
    yp[4*64] = pk2(acc10.x, acc10.y);
    yp[5*64] = pk2(acc10.z, acc10.w);
    yp[6*64] = pk2(acc11.x, acc11.y);
    yp[7*64] = pk2(acc11.z, acc11.w);
    yp[8*64] = fasu(accL0.x);
    yp[9*64] = fasu(accL1.x);
  }
  __syncthreads();
  if (kh >= 4) return;
  int ct = kh;
  f32x4 a00 = z4, a01 = z4, a10 = z4, a11 = z4;
  float l0 = 0.f, l1 = 0.f;
  #pragma unroll
  for (int k = 0; k < 8; ++k) {
    const unsigned* q = &sm.ypk[k][0][lane];
    unsigned d0v = q[0], d1v = q[64], d2v = q[128], d3v = q[192];
    unsigned d4v = q[256], d5v = q[320], d6v = q[384], d7v = q[448];
    a00.x += unlo(d0v); a00.y += unhi(d0v); a00.z += unlo(d1v); a00.w += unhi(d1v);
    a01.x += unlo(d2v); a01.y += unhi(d2v); a01.z += unlo(d3v); a01.w += unhi(d3v);
    a10.x += unlo(d4v); a10.y += unhi(d4v); a10.z += unlo(d5v); a10.w += unhi(d5v);
    a11.x += unlo(d6v); a11.y += unhi(d6v); a11.z += unlo(d7v); a11.w += unhi(d7v);
    l0 += uasf(q[512]); l1 += uasf(q[576]);
  }
  float r0 = 1.f / l0, r1 = 1.f / l1;
  a00 *= r0; a01 *= r0; a10 *= r1; a11 *= r1;
  // transpose D-layout -> B-layout via LDS (ytr aliases plds; safe post-barrier)
  unsigned short* yl = &sm.plds[0][0] + ct*1280;
  *(s16x4*)(yl + l15*40 + quad*4)             = pk4(a00);
  *(s16x4*)(yl + l15*40 + 16 + quad*4)        = pk4(a01);
  *(s16x4*)(yl + (16 + l15)*40 + quad*4)      = pk4(a10);
  *(s16x4*)(yl + (16 + l15)*40 + 16 + quad*4) = pk4(a11);
  bf16x8 y0 = *(const bf16x8*)(yl + l15*40 + quad*8);
  bf16x8 y1 = *(const bf16x8*)(yl + (16 + l15)*40 + quad*8);
  bf16x8 wf = ((const bf16x8*)WzF)[ct*64 + lane];
  f32x4 zq0 = MFMA(wf, y0, z4);
  f32x4 zq1 = MFMA(wf, y1, z4);
  int c0 = ct*16 + quad*4;
  f32x4 b2 = *(const f32x4*)(bias2 + c0);
  int q0i = qblk * 32;
  const float* xp0 = x + (b*64 + c0)*4096 + q0i + l15;
  f32x4 s0, s1;
  s0.x = zq0.x + b2.x + xp0[0];
  s0.y = zq0.y + b2.y + xp0[4096];
  s0.z = zq0.z + b2.z + xp0[8192];
  s0.w = zq0.w + b2.w + xp0[12288];
  s1.x = zq1.x + b2.x + xp0[16];
  s1.y = zq1.y + b2.y + xp0[4096 + 16];
  s1.z = zq1.z + b2.z + xp0[8192 + 16];
  s1.w = zq1.w + b2.w + xp0[12288 + 16];
  {
    int q = q0i + l15, h = q >> 6, w = q & 63;
    *(s16x4*)(z_pad + b*ZPB + ((h + 7)*78 + (w + 7))*64 + c0) = pk4(s0);
    q = q0i + 16 + l15; h = q >> 6; w = q & 63;
    *(s16x4*)(z_pad + b*ZPB + ((h + 7)*78 + (w + 7))*64 + c0) = pk4(s1);
  }
  f32x4 zs = s0 + s1;
  #pragma unroll
  for (int m = 1; m < 16; m <<= 1) {
    zs.x += __shfl_xor(zs.x, m);
    zs.y += __shfl_xor(zs.y, m);
    zs.z += __shfl_xor(zs.z, m);
    zs.w += __shfl_xor(zs.w, m);
  }
  if (l15 == 0) {
    atomicAdd(zmean + b*64 + c0 + 0, zs.x);
    atomicAdd(zmean + b*64 + c0 + 1, zs.y);
    atomicAdd(zmean + b*64 + c0 + 2, zs.z);
    atomicAdd(zmean + b*64 + c0 + 3, zs.w);
  }
}

// ========== k_conv: 28-tap ASPP conv, depth-4 dual (z+w) prefetch ==========
__global__ __launch_bounds__(256, 4) void k_conv(
    const unsigned short* __restrict__ z_pad, const unsigned short* __restrict__ Wfrag,
    const float* __restrict__ zmean, const float* __restrict__ am_wT,
    const float* __restrict__ am_b, const float* __restrict__ owT0,
    const float* __restrict__ cbias, float* __restrict__ out) {
  static constexpr int DYt[28] = {0, -3,-3,-3,0,0,0,3,3,3,
                                     -5,-5,-5,0,0,0,5,5,5,
                                     -7,-7,-7,0,0,0,7,7,7};
  static constexpr int DXt[28] = {0, -3,0,3,-3,0,3,-3,0,3,
                                     -5,0,5,-5,0,5,-5,0,5,
                                     -7,0,7,-7,0,7,-7,0,7};
  int blk = blockIdx.x;                       // b(4) x h(64)
  int b = blk >> 6, h = blk & 63;
  int tid = threadIdx.x;
  int wave = tid >> 6, lane = tid & 63, quad = lane >> 4, l15 = lane & 15;
  int dt2 = wave >> 1, wt2 = wave & 1;
  // inlined c_b (independent; hides under the MFMA loop)
  float zml = zmean[b*64 + lane] * (1.f / 4096.f);
  float img = am_b[lane];
  for (int c = 0; c < 64; ++c) img += am_wT[c*64 + lane] * __shfl(zml, c);
  float cbd = cbias[lane];
  for (int dd = 0; dd < 64; ++dd) cbd += owT0[dd*64 + lane] * __shfl(img, dd);
  // main implicit GEMM: 56 (tap,cc) steps, depth-4 rolling prefetch of z AND w
  const unsigned short* zb = z_pad + b*ZPB + ((h + 7)*78 + 7)*64 + quad*8;
  const bf16x8* wfp = (const bf16x8*)Wfrag + lane;
  int d0 = dt2*2 + 0, d1 = dt2*2 + 1;
  const f32x4 z4 = {0.f, 0.f, 0.f, 0.f};
  f32x4 acc00 = z4, acc01 = z4, acc10 = z4, acc11 = z4;
  int col0 = ((wt2*2 + 0)*16 + l15)*64;
  int col1 = ((wt2*2 + 1)*16 + l15)*64;
  bf16x8 zq0[4], zq1[4], wq0[4], wq1[4];
  #pragma unroll
  for (int p = 0; p < 4; ++p) {
    int tap = p >> 1, cc = p & 1;
    const unsigned short* nz = zb + (DYt[tap]*78 + DXt[tap])*64 + cc*32;
    zq0[p] = *(const bf16x8*)(nz + col0);
    zq1[p] = *(const bf16x8*)(nz + col1);
    wq0[p] = wfp[((tap*4 + d0)*2 + cc)*64];
    wq1[p] = wfp[((tap*4 + d1)*2 + cc)*64];
  }
  #pragma unroll
  for (int idx = 0; idx < 56; ++idx) {
    int slot = idx & 3;
    bf16x8 zc0 = zq0[slot], zc1 = zq1[slot], wc0 = wq0[slot], wc1 = wq1[slot];
    if (idx + 4 < 56) {
      int ntap = (idx + 4) >> 1, ncc = (idx + 4) & 1;
      const unsigned short* nz = zb + (DYt[ntap]*78 + DXt[ntap])*64 + ncc*32;
      zq0[slot] = *(const bf16x8*)(nz + col0);
      zq1[slot] = *(const bf16x8*)(nz + col1);
      wq0[slot] = wfp[((ntap*4 + d0)*2 + ncc)*64];
      wq1[slot] = wfp[((ntap*4 + d1)*2 + ncc)*64];
    }
    acc00 = MFMA(wc0, zc0, acc00);
    acc01 = MFMA(wc0, zc1, acc01);
    acc10 = MFMA(wc1, zc0, acc10);
    acc11 = MFMA(wc1, zc1, acc11);
  }
  int dd0 = d0*16 + quad*4, dd1 = d1*16 + quad*4;
  f32x4 cb0v, cb1v;
  cb0v.x = __shfl(cbd, dd0 + 0); cb0v.y = __shfl(cbd, dd0 + 1);
  cb0v.z = __shfl(cbd, dd0 + 2); cb0v.w = __shfl(cbd, dd0 + 3);
  cb1v.x = __shfl(cbd, dd1 + 0); cb1v.y = __shfl(cbd, dd1 + 1);
  cb1v.z = __shfl(cbd, dd1 + 2); cb1v.w = __shfl(cbd, dd1 + 3);
  acc00 += cb0v; acc01 += cb0v; acc10 += cb1v; acc11 += cb1v;
  float* ob = out + b*262144 + h*64;
  int w0 = (wt2*2 + 0)*16 + l15, w1 = (wt2*2 + 1)*16 + l15;
  ob[(dd0 + 0)*4096 + w0] = acc00.x;
  ob[(dd0 + 1)*4096 + w0] = acc00.y;
  ob[(dd0 + 2)*4096 + w0] = acc00.z;
  ob[(dd0 + 3)*4096 + w0] = acc00.w;
  ob[(dd0 + 0)*4096 + w1] = acc01.x;
  ob[(dd0 + 1)*4096 + w1] = acc01.y;
  ob[(dd0 + 2)*4096 + w1] = acc01.z;
  ob[(dd0 + 3)*4096 + w1] = acc01.w;
  ob[(dd1 + 0)*4096 + w0] = acc10.x;
  ob[(dd1 + 1)*4096 + w0] = acc10.y;
  ob[(dd1 + 2)*4096 + w0] = acc10.z;
  ob[(dd1 + 3)*4096 + w0] = acc10.w;
  ob[(dd1 + 0)*4096 + w1] = acc11.x;
  ob[(dd1 + 1)*4096 + w1] = acc11.y;
  ob[(dd1 + 2)*4096 + w1] = acc11.z;
  ob[(dd1 + 3)*4096 + w1] = acc11.w;
}

extern "C" void kernel_launch(void* const* d_in, const int* in_sizes, int n_in,
                              void* d_out, int out_size, void* d_ws, size_t ws_size,
                              hipStream_t stream) {
  const float* x    = (const float*)d_in[0];
  const float* g_w  = (const float*)d_in[1];
  const float* g_b  = (const float*)d_in[2];
  const float* th_w = (const float*)d_in[3];
  const float* th_b = (const float*)d_in[4];
  const float* ph_w = (const float*)d_in[5];
  const float* ph_b = (const float*)d_in[6];
  const float* Wz_w = (const float*)d_in[7];
  const float* Wz_b = (const float*)d_in[8];
  const float* bn_g = (const float*)d_in[9];
  const float* bn_b = (const float*)d_in[10];
  const float* am_w = (const float*)d_in[11];
  const float* am_b = (const float*)d_in[12];
  const float* a1_w = (const float*)d_in[13];
  const float* a1_b = (const float*)d_in[14];
  const float* a3_w = (const float*)d_in[15];
  const float* a3_b = (const float*)d_in[16];
  const float* a5_w = (const float*)d_in[17];
  const float* a5_b = (const float*)d_in[18];
  const float* a7_w = (const float*)d_in[19];
  const float* a7_b = (const float*)d_in[20];
  const float* out_w = (const float*)d_in[21];
  const float* out_b = (const float*)d_in[22];
  float* out = (float*)d_out;
  char* ws = (char*)d_ws;
  unsigned short* thetaB = (unsigned short*)(ws + 0);
  unsigned short* phiB   = (unsigned short*)(ws + 1048576);
  unsigned short* gB     = (unsigned short*)(ws + 2097152);
  unsigned short* z_pad  = (unsigned short*)(ws + 3145728);
  unsigned short* Wfrag  = (unsigned short*)(ws + 6260736);
  unsigned short* WzF    = (unsigned short*)(ws + 6490112);
  float* zmean           = (float*)(ws + 6494208);
  float* bias2           = (float*)(ws + 6495232);
  float* am_wT           = (float*)(ws + 6495488);
  float* owT0            = (float*)(ws + 6511872);
  float* cbias           = (float*)(ws + 6528256);

  k_proj<<<dim3(1218), dim3(256), 0, stream>>>(
      x, th_w, th_b, ph_w, ph_b, g_w, g_b, Wz_w, Wz_b, bn_g, bn_b,
      out_w, out_b, a1_w, a3_w, a5_w, a7_w, a1_b, a3_b, a5_b, a7_b, am_w,
      thetaB, phiB, gB, WzF, bias2, zmean,
      (unsigned*)z_pad, Wfrag, am_wT, owT0, cbias);
  k_attn<<<dim3(512), dim3(512), 0, stream>>>(thetaB, phiB, gB, WzF, bias2, x,
                                              z_pad, zmean);
  k_conv<<<dim3(256), dim3(256), 0, stream>>>(z_pad, Wfrag, zmean, am_wT, am_b,
                                              owT0, cbias, out);
}

// Round 8
// 162.526 us; speedup vs baseline: 1.1659x; 1.1118x over previous
//
#include <hip/hip_runtime.h>

// NonLocal (flash attention, d=32) + collapsed ASPP, all MFMA bf16 on gfx950.
// 3 dispatches:
//   k_proj: QKV (LDS-transposed weights, float4 reads, ci-split threads)
//           + WzF/bias2/zpart + halo zero + Wfrag + transposes
//   k_attn: 1024 blocks (q-split 16) x 8 waves, K-split 8 in-block,
//           LDS 19.5KB -> 4 blocks/CU (32 waves/CU). XCD-swizzled.
//   k_conv: 28-tap implicit GEMM, 512 blocks XCD-swizzled into h-bands
//           (L2-resident z), depth-4 dual prefetch.
// Layout conventions (A: m=lane&15,k=quad*8+j | B: n=lane&15,k=quad*8+j |
//                     D: n=lane&15,m=quad*4+r)

typedef __attribute__((ext_vector_type(8))) short bf16x8;
typedef __attribute__((ext_vector_type(4))) short s16x4;
typedef __attribute__((ext_vector_type(4))) float f32x4;

#define MFMA(a, b, c) __builtin_amdgcn_mfma_f32_16x16x32_bf16((a), (b), (c), 0, 0, 0)

#if __has_builtin(__builtin_amdgcn_exp2f)
#define EXP2(x) __builtin_amdgcn_exp2f(x)
#else
#define EXP2(x) exp2f(x)
#endif

__device__ static inline short f2bf(float f) {
  union { float f; unsigned u; } v; v.f = f;
  unsigned r = v.u + 0x7fffu + ((v.u >> 16) & 1u);
  return (short)(r >> 16);
}
__device__ static inline s16x4 pk4(f32x4 v) {
  s16x4 r; r.x = f2bf(v.x); r.y = f2bf(v.y); r.z = f2bf(v.z); r.w = f2bf(v.w);
  return r;
}
// truncating 2xfp32 -> packed bf16x2 dword (low16 = f0, high16 = f1)
__device__ static inline unsigned pk2(float f0, float f1) {
  union { float f; unsigned u; } a, b; a.f = f0; b.f = f1;
  return __builtin_amdgcn_perm(b.u, a.u, 0x07060302u);
}
__device__ static inline float unlo(unsigned d) {
  union { unsigned u; float f; } v; v.u = d << 16; return v.f;
}
__device__ static inline float unhi(unsigned d) {
  union { unsigned u; float f; } v; v.u = d & 0xffff0000u; return v.f;
}
__device__ static inline unsigned fasu(float f) {
  union { float f; unsigned u; } v; v.f = f; return v.u;
}
__device__ static inline float uasf(unsigned u) {
  union { unsigned u; float f; } v; v.u = u; return v.f;
}
__device__ static inline f32x4 exp24(f32x4 v) {
  f32x4 r; r.x = EXP2(v.x); r.y = EXP2(v.y); r.z = EXP2(v.z); r.w = EXP2(v.w);
  return r;
}

#define QF_PER_B 131072
#define ZPB      389376
#define LOG2E    1.4426950408889634f

// ====== k_proj: QKV + WzF/bias2/zpart + halo zero + Wfrag + transposes ======
// blocks [0,384): QKV (proj x b x pt). 384: WzF/bias2/zpart-zero.
// [385,1381): halo zero. [1381,1409): Wfrag taps. 1409: transposes + cbias.
__global__ __launch_bounds__(256) void k_proj(
    const float* __restrict__ x,
    const float* __restrict__ tw, const float* __restrict__ tb,
    const float* __restrict__ pw, const float* __restrict__ pb,
    const float* __restrict__ gw, const float* __restrict__ gb,
    const float* __restrict__ Wz_w, const float* __restrict__ Wz_b,
    const float* __restrict__ bn_g, const float* __restrict__ bn_b,
    const float* __restrict__ out_w, const float* __restrict__ out_b,
    const float* __restrict__ a1_w, const float* __restrict__ a3_w,
    const float* __restrict__ a5_w, const float* __restrict__ a7_w,
    const float* __restrict__ a1_b, const float* __restrict__ a3_b,
    const float* __restrict__ a5_b, const float* __restrict__ a7_b,
    const float* __restrict__ am_w,
    unsigned short* __restrict__ thetaB, unsigned short* __restrict__ phiB,
    unsigned short* __restrict__ gB, unsigned short* __restrict__ WzF,
    float* __restrict__ bias2, float* __restrict__ zpart,
    unsigned* __restrict__ zp, unsigned short* __restrict__ Wfrag,
    float* __restrict__ am_wT, float* __restrict__ owT0,
    float* __restrict__ cbias) {
  __shared__ union {
    struct { float wlT[2048]; float bl[32]; } qkv;   // wlT[c][ci]
    struct { float wsm[4096]; float osm[64 * 65]; } prep;
  } sm;
  int blk = blockIdx.x, t = threadIdx.x;
  if (blk < 384) {
    int proj = blk >> 7, r = blk & 127;
    int b = r & 3, pt = r >> 2;                 // pt in [0,32): 128 px each
    const float* w    = proj == 0 ? tw : (proj == 1 ? pw : gw);
    const float* bias = proj == 0 ? tb : (proj == 1 ? pb : gb);
    for (int i = t; i < 2048; i += 256)
      sm.qkv.wlT[(i & 63) * 32 + (i >> 6)] = w[i];   // transpose: [c][ci]
    if (t < 32) sm.qkv.bl[t] = bias[t];
    __syncthreads();
    int px = pt * 128 + (t & 127), tci = t >> 7;     // thread covers 16 ci
    const float* xp = x + b*64*4096 + px;
    float acc[16];
    #pragma unroll
    for (int i = 0; i < 16; ++i) acc[i] = sm.qkv.bl[tci*16 + i];
    for (int c0 = 0; c0 < 64; c0 += 16) {
      float xv[16];
      #pragma unroll
      for (int k = 0; k < 16; ++k) xv[k] = xp[(c0 + k)*4096];
      #pragma unroll
      for (int k = 0; k < 16; ++k) {
        const float* wr = &sm.qkv.wlT[(c0 + k)*32 + tci*16];
        #pragma unroll
        for (int j = 0; j < 4; ++j) {
          f32x4 wv = *(const f32x4*)(wr + j*4);
          acc[j*4 + 0] += wv.x * xv[k];
          acc[j*4 + 1] += wv.y * xv[k];
          acc[j*4 + 2] += wv.z * xv[k];
          acc[j*4 + 3] += wv.w * xv[k];
        }
      }
    }
    if (proj == 0) {
      #pragma unroll
      for (int i = 0; i < 16; ++i) acc[i] *= LOG2E;
    }
    if (proj < 2) {
      unsigned short* base = (proj == 0 ? thetaB : phiB) + b*QF_PER_B
                             + (px >> 4)*512 + (px & 15)*8;
      #pragma unroll
      for (int qq = 0; qq < 2; ++qq) {
        bf16x8 v;
        #pragma unroll
        for (int j = 0; j < 8; ++j) v[j] = f2bf(acc[qq*8 + j]);
        *(bf16x8*)(base + (tci*2 + qq)*128) = v;
      }
    } else {
      unsigned short* base = gB + b*QF_PER_B + (px >> 5)*1024
                             + ((px & 31) >> 3)*128 + (px & 7) + tci*512;
      #pragma unroll
      for (int ci = 0; ci < 16; ++ci)
        base[ci*8] = (unsigned short)f2bf(acc[ci]);
    }
  } else if (blk == 384) {
    int ct = t >> 6, lane = t & 63, quad = lane >> 4, l15 = lane & 15;
    int c = ct * 16 + l15;
    float s = bn_g[c] * rsqrtf(1.f + 1e-5f);
    bf16x8 v;
    #pragma unroll
    for (int j = 0; j < 8; ++j) v[j] = f2bf(s * Wz_w[c * 32 + quad * 8 + j]);
    *(bf16x8*)(WzF + (ct * 64 + lane) * 8) = v;
    #pragma unroll
    for (int i = 0; i < 8; ++i) zpart[i*256 + t] = 0.f;
    if (t < 64) {
      float s2 = bn_g[t] * rsqrtf(1.f + 1e-5f);
      bias2[t] = s2 * Wz_b[t] + bn_b[t];
    }
  } else if (blk < 1381) {
    // z_pad halo zero: rows 0-6 & 71-77 full width; rows 7-70 cols 0-6 & 71-77
    int hb = blk - 385;
    int b = hb / 249, loc = hb - b * 249;
    int i = loc * 256 + t;
    if (i >= 63616) return;
    int px = i >> 5, dw = i & 31;
    int row, col;
    if (px < 1092) {
      int r = px / 78; col = px - r * 78;
      row = (r < 7) ? r : r + 64;
    } else {
      int j = px - 1092;
      int r = j / 14; int c = j - r * 14;
      row = r + 7; col = (c < 7) ? c : c + 64;   // right halo = 71..77
    }
    zp[b * (ZPB / 2) + (row * 78 + col) * 32 + dw] = 0u;
  } else if (blk < 1409) {
    int tap = blk - 1381;
    const float* w; int goff, kyx = 0, ksq = 9;
    if (tap == 0)      { w = a1_w; goff = 64;  ksq = 1; }
    else if (tap < 10) { w = a3_w; goff = 128; kyx = tap - 1; }
    else if (tap < 19) { w = a5_w; goff = 192; kyx = tap - 10; }
    else               { w = a7_w; goff = 256; kyx = tap - 19; }
    for (int i = t; i < 4096; i += 256) {
      sm.prep.wsm[i] = w[i * ksq + kyx];
      int d = i >> 6, m = i & 63;
      sm.prep.osm[d * 65 + m] = out_w[d * 320 + goff + m];
    }
    __syncthreads();
    int dt = t >> 6, lane = t & 63, quad = lane >> 4, l15 = lane & 15;
    int d = dt * 16 + l15;
    float acc[16];
    #pragma unroll
    for (int k = 0; k < 16; ++k) acc[k] = 0.f;
    const float* orow = sm.prep.osm + d * 65;
    int c0 = quad * 8;
    for (int m = 0; m < 64; ++m) {
      float o = orow[m];
      const float* wr = sm.prep.wsm + m * 64 + c0;
      #pragma unroll
      for (int cc = 0; cc < 2; ++cc)
        #pragma unroll
        for (int j = 0; j < 8; ++j)
          acc[cc * 8 + j] += o * wr[cc * 32 + j];
    }
    #pragma unroll
    for (int cc = 0; cc < 2; ++cc) {
      bf16x8 v;
      #pragma unroll
      for (int j = 0; j < 8; ++j) v[j] = f2bf(acc[cc * 8 + j]);
      *(bf16x8*)(Wfrag + (((tap * 4 + dt) * 2 + cc) * 64 + lane) * 8) = v;
    }
  } else {
    for (int i = t; i < 4096; i += 256) {
      int d = i >> 6, c = i & 63;
      am_wT[c * 64 + d] = am_w[i];
      owT0[c * 64 + d] = out_w[d * 320 + c];
    }
    if (t < 64) {
      float r = out_b[t];
      const float* ow = out_w + t * 320;
      for (int m = 0; m < 64; ++m)
        r += ow[64 + m] * a1_b[m] + ow[128 + m] * a3_b[m]
           + ow[192 + m] * a5_b[m] + ow[256 + m] * a7_b[m];
      cbias[t] = r;
    }
  }
}

// ====== k_attn: flash attention, 16 q/block, K-split=8, fused merge ======
// 1024 blocks, LDS 19,456 B -> 4 blocks/CU (32 waves/CU). XCD-swizzled:
// xcd = blk&7 -> batch (xcd>>1), q-half (xcd&1): ~1 MB working set per XCD.
__global__ __launch_bounds__(512, 8) void k_attn(
    const unsigned short* __restrict__ thetaB, const unsigned short* __restrict__ phiB,
    const unsigned short* __restrict__ gB, const unsigned short* __restrict__ WzF,
    const float* __restrict__ bias2, const float* __restrict__ x,
    unsigned short* __restrict__ z_pad, float* __restrict__ zpart) {
  __shared__ struct {
    unsigned ypk[8][5][64];                  // [wave][dword][lane]: 4 y + 1 l
    __align__(16) unsigned short plds[8][576];
  } sm;
  int blk = blockIdx.x;
  int xcd = blk & 7;
  int b = xcd >> 1;
  int qblk = ((xcd & 1) << 7) | (blk >> 3);   // [0,256): 16-px q tile
  int tid = threadIdx.x;
  int kh = tid >> 6, lane = tid & 63, quad = lane >> 4, l15 = lane & 15;
  const bf16x8* thB = (const bf16x8*)(thetaB + b*QF_PER_B);
  const bf16x8* phF = (const bf16x8*)(phiB + b*QF_PER_B);
  const bf16x8* gF  = (const bf16x8*)(gB + b*QF_PER_B);
  bf16x8 th = thB[qblk*64 + lane];
  bf16x8 ones;
  #pragma unroll
  for (int j = 0; j < 8; ++j) ones[j] = (short)0x3F80;
  const f32x4 z4 = {0.f, 0.f, 0.f, 0.f};
  f32x4 acc0 = z4, acc1 = z4, accL = z4;
  unsigned short* pl = &sm.plds[kh][0];
  unsigned short* rp = pl + l15*36 + quad*4;
  const unsigned short* qp = pl + l15*36 + quad*8;
  int kt0 = kh*16;
  int tb0 = kt0*128 + lane;
  bf16x8 pf0 = phF[tb0], pf1 = phF[tb0 + 64];
  for (int kt = kt0; kt < kt0 + 16; ++kt) {
    bf16x8 cp0 = pf0, cp1 = pf1;
    bf16x8 gf0 = gF[kt*128 + lane];
    bf16x8 gf1 = gF[kt*128 + lane + 64];
    if (kt + 1 < kt0 + 16) {                 // prefetch next phi pair
      int tb = (kt + 1)*128 + lane;
      pf0 = phF[tb]; pf1 = phF[tb + 64];
    }
    f32x4 s0 = MFMA(cp0, th, z4);            // S^T[k0..15][q]
    f32x4 s1 = MFMA(cp1, th, z4);            // S^T[k16..31][q]
    f32x4 p0 = exp24(s0), p1 = exp24(s1);
    uint2 w0; w0.x = pk2(p0.x, p0.y); w0.y = pk2(p0.z, p0.w);
    uint2 w1; w1.x = pk2(p1.x, p1.y); w1.y = pk2(p1.z, p1.w);
    *(uint2*)(rp)      = w0;
    *(uint2*)(rp + 16) = w1;
    uint2 a0 = *(const uint2*)(qp);
    uint2 a1 = *(const uint2*)(qp + 4);
    union { unsigned u[4]; bf16x8 v; } pb;
    pb.u[0] = a0.x; pb.u[1] = a0.y; pb.u[2] = a1.x; pb.u[3] = a1.y;
    acc0 = MFMA(gf0, pb.v, acc0);            // Y^T[ci 0..15][q]
    acc1 = MFMA(gf1, pb.v, acc1);            // ci 16..31
    accL = MFMA(ones, pb.v, accL);           // l(q) in every lane
  }
  {
    unsigned* yp = &sm.ypk[kh][0][lane];
    yp[0*64] = pk2(acc0.x, acc0.y);
    yp[1*64] = pk2(acc0.z, acc0.w);
    yp[2*64] = pk2(acc1.x, acc1.y);
    yp[3*64] = pk2(acc1.z, acc1.w);
    yp[4*64] = fasu(accL.x);
  }
  __syncthreads();
  if (kh >= 4) return;
  int ct = kh;
  f32x4 a0 = z4, a1 = z4;
  float l = 0.f;
  #pragma unroll
  for (int k = 0; k < 8; ++k) {
    const unsigned* q = &sm.ypk[k][0][lane];
    unsigned d0v = q[0], d1v = q[64], d2v = q[128], d3v = q[192];
    a0.x += unlo(d0v); a0.y += unhi(d0v); a0.z += unlo(d1v); a0.w += unhi(d1v);
    a1.x += unlo(d2v); a1.y += unhi(d2v); a1.z += unlo(d3v); a1.w += unhi(d3v);
    l += uasf(q[256]);
  }
  float rl = 1.f / l;
  a0 *= rl; a1 *= rl;
  // transpose D-layout (q=l15, ci=quad*4+r) -> B-layout via LDS (alias plds[ct])
  unsigned short* yl = &sm.plds[ct][0];
  *(s16x4*)(yl + l15*36 + quad*4)      = pk4(a0);
  *(s16x4*)(yl + l15*36 + 16 + quad*4) = pk4(a1);
  bf16x8 y = *(const bf16x8*)(yl + l15*36 + quad*8);
  bf16x8 wf = ((const bf16x8*)WzF)[ct*64 + lane];
  f32x4 zq = MFMA(wf, y, z4);                // z[c=ct*16+quad*4+r][q=l15]
  int c0 = ct*16 + quad*4;
  f32x4 b2 = *(const f32x4*)(bias2 + c0);
  int q = qblk*16 + l15;
  const float* xp = x + (b*64 + c0)*4096 + q;
  f32x4 s;
  s.x = zq.x + b2.x + xp[0];
  s.y = zq.y + b2.y + xp[4096];
  s.z = zq.z + b2.z + xp[8192];
  s.w = zq.w + b2.w + xp[12288];
  int h = q >> 6, w = q & 63;
  *(s16x4*)(z_pad + b*ZPB + ((h + 7)*78 + (w + 7))*64 + c0) = pk4(s);
  // zmean partial (spread over 8 slots to cut atomic contention)
  f32x4 zs = s;
  #pragma unroll
  for (int m = 1; m < 16; m <<= 1) {
    zs.x += __shfl_xor(zs.x, m);
    zs.y += __shfl_xor(zs.y, m);
    zs.z += __shfl_xor(zs.z, m);
    zs.w += __shfl_xor(zs.w, m);
  }
  if (l15 == 0) {
    float* zd = zpart + (qblk & 7)*256 + b*64 + c0;
    atomicAdd(zd + 0, zs.x);
    atomicAdd(zd + 1, zs.y);
    atomicAdd(zd + 2, zs.z);
    atomicAdd(zd + 3, zs.w);
  }
}

// ========== k_conv: 28-tap ASPP conv, XCD h-bands, depth-4 prefetch ==========
// 512 blocks: xcd = blk&7 owns h in [8*xcd, 8*xcd+8) -> z rows L2-resident.
// Block = (b, h, wh:32 cols); 4 waves = dt2(2) x colfrag(2).
__global__ __launch_bounds__(256, 4) void k_conv(
    const unsigned short* __restrict__ z_pad, const unsigned short* __restrict__ Wfrag,
    const float* __restrict__ zpart, const float* __restrict__ am_wT,
    const float* __restrict__ am_b, const float* __restrict__ owT0,
    const float* __restrict__ cbias, float* __restrict__ out) {
  static constexpr int DYt[28] = {0, -3,-3,-3,0,0,0,3,3,3,
                                     -5,-5,-5,0,0,0,5,5,5,
                                     -7,-7,-7,0,0,0,7,7,7};
  static constexpr int DXt[28] = {0, -3,0,3,-3,0,3,-3,0,3,
                                     -5,0,5,-5,0,5,-5,0,5,
                                     -7,0,7,-7,0,7,-7,0,7};
  int blk = blockIdx.x;
  int xcd = blk & 7, idx = blk >> 3;
  int h = xcd*8 + (idx & 7);
  int rest = idx >> 3;
  int b = rest & 3, wh = rest >> 2;
  int tid = threadIdx.x;
  int wave = tid >> 6, lane = tid & 63, quad = lane >> 4, l15 = lane & 15;
  int dt2 = wave >> 1, cf = wave & 1;
  // inlined c_b (independent; hides under the MFMA loop)
  float zm = 0.f;
  #pragma unroll
  for (int p = 0; p < 8; ++p) zm += zpart[p*256 + b*64 + lane];
  float zml = zm * (1.f / 4096.f);
  float img = am_b[lane];
  for (int c = 0; c < 64; ++c) img += am_wT[c*64 + lane] * __shfl(zml, c);
  float cbd = cbias[lane];
  for (int dd = 0; dd < 64; ++dd) cbd += owT0[dd*64 + lane] * __shfl(img, dd);
  // main implicit GEMM: 56 (tap,cc) steps, depth-4 prefetch of z AND w
  const unsigned short* zb = z_pad + b*ZPB + ((h + 7)*78 + 7)*64 + quad*8;
  const bf16x8* wfp = (const bf16x8*)Wfrag + lane;
  int d0 = dt2*2 + 0, d1 = dt2*2 + 1;
  const f32x4 z4 = {0.f, 0.f, 0.f, 0.f};
  f32x4 acc0 = z4, acc1 = z4;
  int col = ((wh*2 + cf)*16 + l15)*64;
  bf16x8 zq[4], wq0[4], wq1[4];
  #pragma unroll
  for (int p = 0; p < 4; ++p) {
    int tap = p >> 1, cc = p & 1;
    zq[p] = *(const bf16x8*)(zb + (DYt[tap]*78 + DXt[tap])*64 + cc*32 + col);
    wq0[p] = wfp[((tap*4 + d0)*2 + cc)*64];
    wq1[p] = wfp[((tap*4 + d1)*2 + cc)*64];
  }
  #pragma unroll
  for (int idx2 = 0; idx2 < 56; ++idx2) {
    int slot = idx2 & 3;
    bf16x8 zc = zq[slot], wc0 = wq0[slot], wc1 = wq1[slot];
    if (idx2 + 4 < 56) {
      int ntap = (idx2 + 4) >> 1, ncc = (idx2 + 4) & 1;
      zq[slot] = *(const bf16x8*)(zb + (DYt[ntap]*78 + DXt[ntap])*64 + ncc*32 + col);
      wq0[slot] = wfp[((ntap*4 + d0)*2 + ncc)*64];
      wq1[slot] = wfp[((ntap*4 + d1)*2 + ncc)*64];
    }
    acc0 = MFMA(wc0, zc, acc0);
    acc1 = MFMA(wc1, zc, acc1);
  }
  int dd0 = d0*16 + quad*4, dd1 = d1*16 + quad*4;
  f32x4 cb0v, cb1v;
  cb0v.x = __shfl(cbd, dd0 + 0); cb0v.y = __shfl(cbd, dd0 + 1);
  cb0v.z = __shfl(cbd, dd0 + 2); cb0v.w = __shfl(cbd, dd0 + 3);
  cb1v.x = __shfl(cbd, dd1 + 0); cb1v.y = __shfl(cbd, dd1 + 1);
  cb1v.z = __shfl(cbd, dd1 + 2); cb1v.w = __shfl(cbd, dd1 + 3);
  acc0 += cb0v; acc1 += cb1v;
  float* ob = out + b*262144 + h*64;
  int w0 = (wh*2 + cf)*16 + l15;
  ob[(dd0 + 0)*4096 + w0] = acc0.x;
  ob[(dd0 + 1)*4096 + w0] = acc0.y;
  ob[(dd0 + 2)*4096 + w0] = acc0.z;
  ob[(dd0 + 3)*4096 + w0] = acc0.w;
  ob[(dd1 + 0)*4096 + w0] = acc1.x;
  ob[(dd1 + 1)*4096 + w0] = acc1.y;
  ob[(dd1 + 2)*4096 + w0] = acc1.z;
  ob[(dd1 + 3)*4096 + w0] = acc1.w;
}

extern "C" void kernel_launch(void* const* d_in, const int* in_sizes, int n_in,
                              void* d_out, int out_size, void* d_ws, size_t ws_size,
                              hipStream_t stream) {
  const float* x    = (const float*)d_in[0];
  const float* g_w  = (const float*)d_in[1];
  const float* g_b  = (const float*)d_in[2];
  const float* th_w = (const float*)d_in[3];
  const float* th_b = (const float*)d_in[4];
  const float* ph_w = (const float*)d_in[5];
  const float* ph_b = (const float*)d_in[6];
  const float* Wz_w = (const float*)d_in[7];
  const float* Wz_b = (const float*)d_in[8];
  const float* bn_g = (const float*)d_in[9];
  const float* bn_b = (const float*)d_in[10];
  const float* am_w = (const float*)d_in[11];
  const float* am_b = (const float*)d_in[12];
  const float* a1_w = (const float*)d_in[13];
  const float* a1_b = (const float*)d_in[14];
  const float* a3_w = (const float*)d_in[15];
  const float* a3_b = (const float*)d_in[16];
  const float* a5_w = (const float*)d_in[17];
  const float* a5_b = (const float*)d_in[18];
  const float* a7_w = (const float*)d_in[19];
  const float* a7_b = (const float*)d_in[20];
  const float* out_w = (const float*)d_in[21];
  const float* out_b = (const float*)d_in[22];
  float* out = (float*)d_out;
  char* ws = (char*)d_ws;
  unsigned short* thetaB = (unsigned short*)(ws + 0);
  unsigned short* phiB   = (unsigned short*)(ws + 1048576);
  unsigned short* gB     = (unsigned short*)(ws + 2097152);
  unsigned short* z_pad  = (unsigned short*)(ws + 3145728);
  unsigned short* Wfrag  = (unsigned short*)(ws + 6260736);
  unsigned short* WzF    = (unsigned short*)(ws + 6490112);
  float* bias2           = (float*)(ws + 6495232);
  float* am_wT           = (float*)(ws + 6495488);
  float* owT0            = (float*)(ws + 6511872);
  float* cbias           = (float*)(ws + 6528256);
  float* zpart           = (float*)(ws + 6528512);   // 8x256 f32

  k_proj<<<dim3(1410), dim3(256), 0, stream>>>(
      x, th_w, th_b, ph_w, ph_b, g_w, g_b, Wz_w, Wz_b, bn_g, bn_b,
      out_w, out_b, a1_w, a3_w, a5_w, a7_w, a1_b, a3_b, a5_b, a7_b, am_w,
      thetaB, phiB, gB, WzF, bias2, zpart,
      (unsigned*)z_pad, Wfrag, am_wT, owT0, cbias);
  k_attn<<<dim3(1024), dim3(512), 0, stream>>>(thetaB, phiB, gB, WzF, bias2, x,
                                               z_pad, zpart);
  k_conv<<<dim3(512), dim3(256), 0, stream>>>(z_pad, Wfrag, zpart, am_wT, am_b,
                                              owT0, cbias, out);
}

// Round 9
// 156.010 us; speedup vs baseline: 1.2146x; 1.0418x over previous
//
#include <hip/hip_runtime.h>

// NonLocal (flash attention, d=32) + collapsed ASPP, all MFMA bf16 on gfx950.
// 3 dispatches:
//   k_proj: QKV (LDS-transposed weights, float4 reads) + WzF/bias2/zpart
//           + halo zero + Wfrag + transposes
//   k_attn: 512 blocks x 8 waves, 32 q/block (2 theta frags share each phi/g
//           load -> half the L2 traffic of R8), K-split 8 in-block, slim
//           38.9 KB LDS packed-bf16 merge. XCD-swizzled.
//   k_conv: 28-tap implicit GEMM, XCD h-bands, depth-4 dual prefetch.
// Layout conventions (A: m=lane&15,k=quad*8+j | B: n=lane&15,k=quad*8+j |
//                     D: n=lane&15,m=quad*4+r)

typedef __attribute__((ext_vector_type(8))) short bf16x8;
typedef __attribute__((ext_vector_type(4))) short s16x4;
typedef __attribute__((ext_vector_type(4))) float f32x4;

#define MFMA(a, b, c) __builtin_amdgcn_mfma_f32_16x16x32_bf16((a), (b), (c), 0, 0, 0)

#if __has_builtin(__builtin_amdgcn_exp2f)
#define EXP2(x) __builtin_amdgcn_exp2f(x)
#else
#define EXP2(x) exp2f(x)
#endif

__device__ static inline short f2bf(float f) {
  union { float f; unsigned u; } v; v.f = f;
  unsigned r = v.u + 0x7fffu + ((v.u >> 16) & 1u);
  return (short)(r >> 16);
}
__device__ static inline s16x4 pk4(f32x4 v) {
  s16x4 r; r.x = f2bf(v.x); r.y = f2bf(v.y); r.z = f2bf(v.z); r.w = f2bf(v.w);
  return r;
}
// truncating 2xfp32 -> packed bf16x2 dword (low16 = f0, high16 = f1)
__device__ static inline unsigned pk2(float f0, float f1) {
  union { float f; unsigned u; } a, b; a.f = f0; b.f = f1;
  return __builtin_amdgcn_perm(b.u, a.u, 0x07060302u);
}
__device__ static inline float unlo(unsigned d) {
  union { unsigned u; float f; } v; v.u = d << 16; return v.f;
}
__device__ static inline float unhi(unsigned d) {
  union { unsigned u; float f; } v; v.u = d & 0xffff0000u; return v.f;
}
__device__ static inline unsigned fasu(float f) {
  union { float f; unsigned u; } v; v.f = f; return v.u;
}
__device__ static inline float uasf(unsigned u) {
  union { unsigned u; float f; } v; v.u = u; return v.f;
}
__device__ static inline f32x4 exp24(f32x4 v) {
  f32x4 r; r.x = EXP2(v.x); r.y = EXP2(v.y); r.z = EXP2(v.z); r.w = EXP2(v.w);
  return r;
}

#define QF_PER_B 131072
#define ZPB      389376
#define LOG2E    1.4426950408889634f

// ====== k_proj: QKV + WzF/bias2/zpart + halo zero + Wfrag + transposes ======
// blocks [0,384): QKV (proj x b x pt). 384: WzF/bias2/zpart-zero.
// [385,1381): halo zero. [1381,1409): Wfrag taps. 1409: transposes + cbias.
__global__ __launch_bounds__(256) void k_proj(
    const float* __restrict__ x,
    const float* __restrict__ tw, const float* __restrict__ tb,
    const float* __restrict__ pw, const float* __restrict__ pb,
    const float* __restrict__ gw, const float* __restrict__ gb,
    const float* __restrict__ Wz_w, const float* __restrict__ Wz_b,
    const float* __restrict__ bn_g, const float* __restrict__ bn_b,
    const float* __restrict__ out_w, const float* __restrict__ out_b,
    const float* __restrict__ a1_w, const float* __restrict__ a3_w,
    const float* __restrict__ a5_w, const float* __restrict__ a7_w,
    const float* __restrict__ a1_b, const float* __restrict__ a3_b,
    const float* __restrict__ a5_b, const float* __restrict__ a7_b,
    const float* __restrict__ am_w,
    unsigned short* __restrict__ thetaB, unsigned short* __restrict__ phiB,
    unsigned short* __restrict__ gB, unsigned short* __restrict__ WzF,
    float* __restrict__ bias2, float* __restrict__ zpart,
    unsigned* __restrict__ zp, unsigned short* __restrict__ Wfrag,
    float* __restrict__ am_wT, float* __restrict__ owT0,
    float* __restrict__ cbias) {
  __shared__ union {
    struct { float wlT[2048]; float bl[32]; } qkv;   // wlT[c][ci]
    struct { float wsm[4096]; float osm[64 * 65]; } prep;
  } sm;
  int blk = blockIdx.x, t = threadIdx.x;
  if (blk < 384) {
    int proj = blk >> 7, r = blk & 127;
    int b = r & 3, pt = r >> 2;                 // pt in [0,32): 128 px each
    const float* w    = proj == 0 ? tw : (proj == 1 ? pw : gw);
    const float* bias = proj == 0 ? tb : (proj == 1 ? pb : gb);
    for (int i = t; i < 2048; i += 256)
      sm.qkv.wlT[(i & 63) * 32 + (i >> 6)] = w[i];   // transpose: [c][ci]
    if (t < 32) sm.qkv.bl[t] = bias[t];
    __syncthreads();
    int px = pt * 128 + (t & 127), tci = t >> 7;     // thread covers 16 ci
    const float* xp = x + b*64*4096 + px;
    float acc[16];
    #pragma unroll
    for (int i = 0; i < 16; ++i) acc[i] = sm.qkv.bl[tci*16 + i];
    for (int c0 = 0; c0 < 64; c0 += 16) {
      float xv[16];
      #pragma unroll
      for (int k = 0; k < 16; ++k) xv[k] = xp[(c0 + k)*4096];
      #pragma unroll
      for (int k = 0; k < 16; ++k) {
        const float* wr = &sm.qkv.wlT[(c0 + k)*32 + tci*16];
        #pragma unroll
        for (int j = 0; j < 4; ++j) {
          f32x4 wv = *(const f32x4*)(wr + j*4);
          acc[j*4 + 0] += wv.x * xv[k];
          acc[j*4 + 1] += wv.y * xv[k];
          acc[j*4 + 2] += wv.z * xv[k];
          acc[j*4 + 3] += wv.w * xv[k];
        }
      }
    }
    if (proj == 0) {
      #pragma unroll
      for (int i = 0; i < 16; ++i) acc[i] *= LOG2E;
    }
    if (proj < 2) {
      unsigned short* base = (proj == 0 ? thetaB : phiB) + b*QF_PER_B
                             + (px >> 4)*512 + (px & 15)*8;
      #pragma unroll
      for (int qq = 0; qq < 2; ++qq) {
        bf16x8 v;
        #pragma unroll
        for (int j = 0; j < 8; ++j) v[j] = f2bf(acc[qq*8 + j]);
        *(bf16x8*)(base + (tci*2 + qq)*128) = v;
      }
    } else {
      unsigned short* base = gB + b*QF_PER_B + (px >> 5)*1024
                             + ((px & 31) >> 3)*128 + (px & 7) + tci*512;
      #pragma unroll
      for (int ci = 0; ci < 16; ++ci)
        base[ci*8] = (unsigned short)f2bf(acc[ci]);
    }
  } else if (blk == 384) {
    int ct = t >> 6, lane = t & 63, quad = lane >> 4, l15 = lane & 15;
    int c = ct * 16 + l15;
    float s = bn_g[c] * rsqrtf(1.f + 1e-5f);
    bf16x8 v;
    #pragma unroll
    for (int j = 0; j < 8; ++j) v[j] = f2bf(s * Wz_w[c * 32 + quad * 8 + j]);
    *(bf16x8*)(WzF + (ct * 64 + lane) * 8) = v;
    #pragma unroll
    for (int i = 0; i < 8; ++i) zpart[i*256 + t] = 0.f;
    if (t < 64) {
      float s2 = bn_g[t] * rsqrtf(1.f + 1e-5f);
      bias2[t] = s2 * Wz_b[t] + bn_b[t];
    }
  } else if (blk < 1381) {
    // z_pad halo zero: rows 0-6 & 71-77 full width; rows 7-70 cols 0-6 & 71-77
    int hb = blk - 385;
    int b = hb / 249, loc = hb - b * 249;
    int i = loc * 256 + t;
    if (i >= 63616) return;
    int px = i >> 5, dw = i & 31;
    int row, col;
    if (px < 1092) {
      int r = px / 78; col = px - r * 78;
      row = (r < 7) ? r : r + 64;
    } else {
      int j = px - 1092;
      int r = j / 14; int c = j - r * 14;
      row = r + 7; col = (c < 7) ? c : c + 64;   // right halo = 71..77
    }
    zp[b * (ZPB / 2) + (row * 78 + col) * 32 + dw] = 0u;
  } else if (blk < 1409) {
    int tap = blk - 1381;
    const float* w; int goff, kyx = 0, ksq = 9;
    if (tap == 0)      { w = a1_w; goff = 64;  ksq = 1; }
    else if (tap < 10) { w = a3_w; goff = 128; kyx = tap - 1; }
    else if (tap < 19) { w = a5_w; goff = 192; kyx = tap - 10; }
    else               { w = a7_w; goff = 256; kyx = tap - 19; }
    for (int i = t; i < 4096; i += 256) {
      sm.prep.wsm[i] = w[i * ksq + kyx];
      int d = i >> 6, m = i & 63;
      sm.prep.osm[d * 65 + m] = out_w[d * 320 + goff + m];
    }
    __syncthreads();
    int dt = t >> 6, lane = t & 63, quad = lane >> 4, l15 = lane & 15;
    int d = dt * 16 + l15;
    float acc[16];
    #pragma unroll
    for (int k = 0; k < 16; ++k) acc[k] = 0.f;
    const float* orow = sm.prep.osm + d * 65;
    int c0 = quad * 8;
    for (int m = 0; m < 64; ++m) {
      float o = orow[m];
      const float* wr = sm.prep.wsm + m * 64 + c0;
      #pragma unroll
      for (int cc = 0; cc < 2; ++cc)
        #pragma unroll
        for (int j = 0; j < 8; ++j)
          acc[cc * 8 + j] += o * wr[cc * 32 + j];
    }
    #pragma unroll
    for (int cc = 0; cc < 2; ++cc) {
      bf16x8 v;
      #pragma unroll
      for (int j = 0; j < 8; ++j) v[j] = f2bf(acc[cc * 8 + j]);
      *(bf16x8*)(Wfrag + (((tap * 4 + dt) * 2 + cc) * 64 + lane) * 8) = v;
    }
  } else {
    for (int i = t; i < 4096; i += 256) {
      int d = i >> 6, c = i & 63;
      am_wT[c * 64 + d] = am_w[i];
      owT0[c * 64 + d] = out_w[d * 320 + c];
    }
    if (t < 64) {
      float r = out_b[t];
      const float* ow = out_w + t * 320;
      for (int m = 0; m < 64; ++m)
        r += ow[64 + m] * a1_b[m] + ow[128 + m] * a3_b[m]
           + ow[192 + m] * a5_b[m] + ow[256 + m] * a7_b[m];
      cbias[t] = r;
    }
  }
}

// ====== k_attn: flash attention, 32 q/block, K-split=8, fused merge ======
// 512 blocks x 8 waves; each phi/g fragment load feeds TWO theta fragments
// (halves L2 read traffic vs 16q). LDS 38,912 B. XCD-swizzled: xcd=blk&7 ->
// batch(xcd>>1), q-half(xcd&1).
__global__ __launch_bounds__(512, 4) void k_attn(
    const unsigned short* __restrict__ thetaB, const unsigned short* __restrict__ phiB,
    const unsigned short* __restrict__ gB, const unsigned short* __restrict__ WzF,
    const float* __restrict__ bias2, const float* __restrict__ x,
    unsigned short* __restrict__ z_pad, float* __restrict__ zpart) {
  __shared__ struct {
    unsigned ypk[8][10][64];                 // [wave][dword][lane]: 8 y + 2 l
    __align__(16) unsigned short plds[8][1152];  // 2 qt x 16 rows x 36
  } sm;
  int blk = blockIdx.x;
  int xcd = blk & 7;
  int b = xcd >> 1;
  int qblk = ((xcd & 1) << 6) | (blk >> 3);   // [0,128): 32-px q tile
  int tid = threadIdx.x;
  int kh = tid >> 6, lane = tid & 63, quad = lane >> 4, l15 = lane & 15;
  const bf16x8* thB = (const bf16x8*)(thetaB + b*QF_PER_B);
  const bf16x8* phF = (const bf16x8*)(phiB + b*QF_PER_B);
  const bf16x8* gF  = (const bf16x8*)(gB + b*QF_PER_B);
  bf16x8 th0 = thB[(qblk*2 + 0)*64 + lane];
  bf16x8 th1 = thB[(qblk*2 + 1)*64 + lane];
  bf16x8 ones;
  #pragma unroll
  for (int j = 0; j < 8; ++j) ones[j] = (short)0x3F80;
  const f32x4 z4 = {0.f, 0.f, 0.f, 0.f};
  f32x4 acc00 = z4, acc01 = z4, acc10 = z4, acc11 = z4;
  f32x4 accL0 = z4, accL1 = z4;
  unsigned short* pl = &sm.plds[kh][0];
  unsigned short* r0p = pl + l15*36 + quad*4;
  unsigned short* r1p = pl + 576 + l15*36 + quad*4;
  const unsigned short* q0p = pl + l15*36 + quad*8;
  const unsigned short* q1p = pl + 576 + l15*36 + quad*8;
  int kt0 = kh*16;
  int tb0 = kt0*128 + lane;
  bf16x8 pf0 = phF[tb0], pf1 = phF[tb0 + 64];
  bf16x8 gf0 = gF[tb0],  gf1 = gF[tb0 + 64];
  for (int kt = kt0; kt < kt0 + 16; ++kt) {
    bf16x8 cp0 = pf0, cp1 = pf1, cg0 = gf0, cg1 = gf1;
    if (kt + 1 < kt0 + 16) {  // prefetch next iteration's fragments
      int tb = (kt + 1)*128 + lane;
      pf0 = phF[tb]; pf1 = phF[tb + 64];
      gf0 = gF[tb];  gf1 = gF[tb + 64];
    }
    f32x4 s00 = MFMA(cp0, th0, z4);   // S^T[k0..15][q of qt0]
    f32x4 s10 = MFMA(cp1, th0, z4);   // S^T[k16..31]
    f32x4 s01 = MFMA(cp0, th1, z4);
    f32x4 s11 = MFMA(cp1, th1, z4);
    f32x4 p00 = exp24(s00), p10 = exp24(s10), p01 = exp24(s01), p11 = exp24(s11);
    uint2 w0; w0.x = pk2(p00.x, p00.y); w0.y = pk2(p00.z, p00.w);
    uint2 w1; w1.x = pk2(p10.x, p10.y); w1.y = pk2(p10.z, p10.w);
    uint2 w2; w2.x = pk2(p01.x, p01.y); w2.y = pk2(p01.z, p01.w);
    uint2 w3; w3.x = pk2(p11.x, p11.y); w3.y = pk2(p11.z, p11.w);
    *(uint2*)(r0p)      = w0;
    *(uint2*)(r0p + 16) = w1;
    *(uint2*)(r1p)      = w2;
    *(uint2*)(r1p + 16) = w3;
    uint2 a0 = *(const uint2*)(q0p);
    uint2 a1 = *(const uint2*)(q0p + 4);
    uint2 b0 = *(const uint2*)(q1p);
    uint2 b1 = *(const uint2*)(q1p + 4);
    union { unsigned u[4]; bf16x8 v; } pb0c, pb1c;
    pb0c.u[0] = a0.x; pb0c.u[1] = a0.y; pb0c.u[2] = a1.x; pb0c.u[3] = a1.y;
    pb1c.u[0] = b0.x; pb1c.u[1] = b0.y; pb1c.u[2] = b1.x; pb1c.u[3] = b1.y;
    acc00 = MFMA(cg0, pb0c.v, acc00);   // Y^T[ci 0..15][q qt0]
    acc01 = MFMA(cg1, pb0c.v, acc01);   // ci 16..31
    acc10 = MFMA(cg0, pb1c.v, acc10);
    acc11 = MFMA(cg1, pb1c.v, acc11);
    accL0 = MFMA(ones, pb0c.v, accL0);
    accL1 = MFMA(ones, pb1c.v, accL1);
  }
  {
    unsigned* yp = &sm.ypk[kh][0][lane];    // stride-64-dword rows: conflict-free
    yp[0*64] = pk2(acc00.x, acc00.y);
    yp[1*64] = pk2(acc00.z, acc00.w);
    yp[2*64] = pk2(acc01.x, acc01.y);
    yp[3*64] = pk2(acc01.z, acc01.w);
    yp[4*64] = pk2(acc10.x, acc10.y);
    yp[5*64] = pk2(acc10.z, acc10.w);
    yp[6*64] = pk2(acc11.x, acc11.y);
    yp[7*64] = pk2(acc11.z, acc11.w);
    yp[8*64] = fasu(accL0.x);
    yp[9*64] = fasu(accL1.x);
  }
  __syncthreads();
  if (kh >= 4) return;
  int ct = kh;
  f32x4 a00 = z4, a01 = z4, a10 = z4, a11 = z4;
  float l0 = 0.f, l1 = 0.f;
  #pragma unroll
  for (int k = 0; k < 8; ++k) {
    const unsigned* q = &sm.ypk[k][0][lane];
    unsigned d0v = q[0], d1v = q[64], d2v = q[128], d3v = q[192];
    unsigned d4v = q[256], d5v = q[320], d6v = q[384], d7v = q[448];
    a00.x += unlo(d0v); a00.y += unhi(d0v); a00.z += unlo(d1v); a00.w += unhi(d1v);
    a01.x += unlo(d2v); a01.y += unhi(d2v); a01.z += unlo(d3v); a01.w += unhi(d3v);
    a10.x += unlo(d4v); a10.y += unhi(d4v); a10.z += unlo(d5v); a10.w += unhi(d5v);
    a11.x += unlo(d6v); a11.y += unhi(d6v); a11.z += unlo(d7v); a11.w += unhi(d7v);
    l0 += uasf(q[512]); l1 += uasf(q[576]);
  }
  float r0 = 1.f / l0, r1 = 1.f / l1;
  a00 *= r0; a01 *= r0; a10 *= r1; a11 *= r1;
  // transpose D-layout -> B-layout via LDS (aliases plds; safe post-barrier)
  unsigned short* yl = &sm.plds[0][0] + ct*1280;
  *(s16x4*)(yl + l15*40 + quad*4)             = pk4(a00);
  *(s16x4*)(yl + l15*40 + 16 + quad*4)        = pk4(a01);
  *(s16x4*)(yl + (16 + l15)*40 + quad*4)      = pk4(a10);
  *(s16x4*)(yl + (16 + l15)*40 + 16 + quad*4) = pk4(a11);
  bf16x8 y0 = *(const bf16x8*)(yl + l15*40 + quad*8);
  bf16x8 y1 = *(const bf16x8*)(yl + (16 + l15)*40 + quad*8);
  bf16x8 wf = ((const bf16x8*)WzF)[ct*64 + lane];
  f32x4 zq0 = MFMA(wf, y0, z4);
  f32x4 zq1 = MFMA(wf, y1, z4);
  int c0 = ct*16 + quad*4;
  f32x4 b2 = *(const f32x4*)(bias2 + c0);
  int q0i = qblk * 32;
  const float* xp0 = x + (b*64 + c0)*4096 + q0i + l15;
  f32x4 s0, s1;
  s0.x = zq0.x + b2.x + xp0[0];
  s0.y = zq0.y + b2.y + xp0[4096];
  s0.z = zq0.z + b2.z + xp0[8192];
  s0.w = zq0.w + b2.w + xp0[12288];
  s1.x = zq1.x + b2.x + xp0[16];
  s1.y = zq1.y + b2.y + xp0[4096 + 16];
  s1.z = zq1.z + b2.z + xp0[8192 + 16];
  s1.w = zq1.w + b2.w + xp0[12288 + 16];
  {
    int q = q0i + l15, h = q >> 6, w = q & 63;
    *(s16x4*)(z_pad + b*ZPB + ((h + 7)*78 + (w + 7))*64 + c0) = pk4(s0);
    q = q0i + 16 + l15; h = q >> 6; w = q & 63;
    *(s16x4*)(z_pad + b*ZPB + ((h + 7)*78 + (w + 7))*64 + c0) = pk4(s1);
  }
  f32x4 zs = s0 + s1;
  #pragma unroll
  for (int m = 1; m < 16; m <<= 1) {
    zs.x += __shfl_xor(zs.x, m);
    zs.y += __shfl_xor(zs.y, m);
    zs.z += __shfl_xor(zs.z, m);
    zs.w += __shfl_xor(zs.w, m);
  }
  if (l15 == 0) {
    float* zd = zpart + (qblk & 7)*256 + b*64 + c0;
    atomicAdd(zd + 0, zs.x);
    atomicAdd(zd + 1, zs.y);
    atomicAdd(zd + 2, zs.z);
    atomicAdd(zd + 3, zs.w);
  }
}

// ========== k_conv: 28-tap ASPP conv, XCD h-bands, depth-4 prefetch ==========
__global__ __launch_bounds__(256, 4) void k_conv(
    const unsigned short* __restrict__ z_pad, const unsigned short* __restrict__ Wfrag,
    const float* __restrict__ zpart, const float* __restrict__ am_wT,
    const float* __restrict__ am_b, const float* __restrict__ owT0,
    const float* __restrict__ cbias, float* __restrict__ out) {
  static constexpr int DYt[28] = {0, -3,-3,-3,0,0,0,3,3,3,
                                     -5,-5,-5,0,0,0,5,5,5,
                                     -7,-7,-7,0,0,0,7,7,7};
  static constexpr int DXt[28] = {0, -3,0,3,-3,0,3,-3,0,3,
                                     -5,0,5,-5,0,5,-5,0,5,
                                     -7,0,7,-7,0,7,-7,0,7};
  int blk = blockIdx.x;
  int xcd = blk & 7, idx = blk >> 3;
  int h = xcd*8 + (idx & 7);
  int rest = idx >> 3;
  int b = rest & 3, wh = rest >> 2;
  int tid = threadIdx.x;
  int wave = tid >> 6, lane = tid & 63, quad = lane >> 4, l15 = lane & 15;
  int dt2 = wave >> 1, cf = wave & 1;
  // inlined c_b (independent; hides under the MFMA loop)
  float zm = 0.f;
  #pragma unroll
  for (int p = 0; p < 8; ++p) zm += zpart[p*256 + b*64 + lane];
  float zml = zm * (1.f / 4096.f);
  float img = am_b[lane];
  for (int c = 0; c < 64; ++c) img += am_wT[c*64 + lane] * __shfl(zml, c);
  float cbd = cbias[lane];
  for (int dd = 0; dd < 64; ++dd) cbd += owT0[dd*64 + lane] * __shfl(img, dd);
  // main implicit GEMM: 56 (tap,cc) steps, depth-4 prefetch of z AND w
  const unsigned short* zb = z_pad + b*ZPB + ((h + 7)*78 + 7)*64 + quad*8;
  const bf16x8* wfp = (const bf16x8*)Wfrag + lane;
  int d0 = dt2*2 + 0, d1 = dt2*2 + 1;
  const f32x4 z4 = {0.f, 0.f, 0.f, 0.f};
  f32x4 acc0 = z4, acc1 = z4;
  int col = ((wh*2 + cf)*16 + l15)*64;
  bf16x8 zq[4], wq0[4], wq1[4];
  #pragma unroll
  for (int p = 0; p < 4; ++p) {
    int tap = p >> 1, cc = p & 1;
    zq[p] = *(const bf16x8*)(zb + (DYt[tap]*78 + DXt[tap])*64 + cc*32 + col);
    wq0[p] = wfp[((tap*4 + d0)*2 + cc)*64];
    wq1[p] = wfp[((tap*4 + d1)*2 + cc)*64];
  }
  #pragma unroll
  for (int idx2 = 0; idx2 < 56; ++idx2) {
    int slot = idx2 & 3;
    bf16x8 zc = zq[slot], wc0 = wq0[slot], wc1 = wq1[slot];
    if (idx2 + 4 < 56) {
      int ntap = (idx2 + 4) >> 1, ncc = (idx2 + 4) & 1;
      zq[slot] = *(const bf16x8*)(zb + (DYt[ntap]*78 + DXt[ntap])*64 + ncc*32 + col);
      wq0[slot] = wfp[((ntap*4 + d0)*2 + ncc)*64];
      wq1[slot] = wfp[((ntap*4 + d1)*2 + ncc)*64];
    }
    acc0 = MFMA(wc0, zc, acc0);
    acc1 = MFMA(wc1, zc, acc1);
  }
  int dd0 = d0*16 + quad*4, dd1 = d1*16 + quad*4;
  f32x4 cb0v, cb1v;
  cb0v.x = __shfl(cbd, dd0 + 0); cb0v.y = __shfl(cbd, dd0 + 1);
  cb0v.z = __shfl(cbd, dd0 + 2); cb0v.w = __shfl(cbd, dd0 + 3);
  cb1v.x = __shfl(cbd, dd1 + 0); cb1v.y = __shfl(cbd, dd1 + 1);
  cb1v.z = __shfl(cbd, dd1 + 2); cb1v.w = __shfl(cbd, dd1 + 3);
  acc0 += cb0v; acc1 += cb1v;
  float* ob = out + b*262144 + h*64;
  int w0 = (wh*2 + cf)*16 + l15;
  ob[(dd0 + 0)*4096 + w0] = acc0.x;
  ob[(dd0 + 1)*4096 + w0] = acc0.y;
  ob[(dd0 + 2)*4096 + w0] = acc0.z;
  ob[(dd0 + 3)*4096 + w0] = acc0.w;
  ob[(dd1 + 0)*4096 + w0] = acc1.x;
  ob[(dd1 + 1)*4096 + w0] = acc1.y;
  ob[(dd1 + 2)*4096 + w0] = acc1.z;
  ob[(dd1 + 3)*4096 + w0] = acc1.w;
}

extern "C" void kernel_launch(void* const* d_in, const int* in_sizes, int n_in,
                              void* d_out, int out_size, void* d_ws, size_t ws_size,
                              hipStream_t stream) {
  const float* x    = (const float*)d_in[0];
  const float* g_w  = (const float*)d_in[1];
  const float* g_b  = (const float*)d_in[2];
  const float* th_w = (const float*)d_in[3];
  const float* th_b = (const float*)d_in[4];
  const float* ph_w = (const float*)d_in[5];
  const float* ph_b = (const float*)d_in[6];
  const float* Wz_w = (const float*)d_in[7];
  const float* Wz_b = (const float*)d_in[8];
  const float* bn_g = (const float*)d_in[9];
  const float* bn_b = (const float*)d_in[10];
  const float* am_w = (const float*)d_in[11];
  const float* am_b = (const float*)d_in[12];
  const float* a1_w = (const float*)d_in[13];
  const float* a1_b = (const float*)d_in[14];
  const float* a3_w = (const float*)d_in[15];
  const float* a3_b = (const float*)d_in[16];
  const float* a5_w = (const float*)d_in[17];
  const float* a5_b = (const float*)d_in[18];
  const float* a7_w = (const float*)d_in[19];
  const float* a7_b = (const float*)d_in[20];
  const float* out_w = (const float*)d_in[21];
  const float* out_b = (const float*)d_in[22];
  float* out = (float*)d_out;
  char* ws = (char*)d_ws;
  unsigned short* thetaB = (unsigned short*)(ws + 0);
  unsigned short* phiB   = (unsigned short*)(ws + 1048576);
  unsigned short* gB     = (unsigned short*)(ws + 2097152);
  unsigned short* z_pad  = (unsigned short*)(ws + 3145728);
  unsigned short* Wfrag  = (unsigned short*)(ws + 6260736);
  unsigned short* WzF    = (unsigned short*)(ws + 6490112);
  float* bias2           = (float*)(ws + 6495232);
  float* am_wT           = (float*)(ws + 6495488);
  float* owT0            = (float*)(ws + 6511872);
  float* cbias           = (float*)(ws + 6528256);
  float* zpart           = (float*)(ws + 6528512);   // 8x256 f32

  k_proj<<<dim3(1410), dim3(256), 0, stream>>>(
      x, th_w, th_b, ph_w, ph_b, g_w, g_b, Wz_w, Wz_b, bn_g, bn_b,
      out_w, out_b, a1_w, a3_w, a5_w, a7_w, a1_b, a3_b, a5_b, a7_b, am_w,
      thetaB, phiB, gB, WzF, bias2, zpart,
      (unsigned*)z_pad, Wfrag, am_wT, owT0, cbias);
  k_attn<<<dim3(512), dim3(512), 0, stream>>>(thetaB, phiB, gB, WzF, bias2, x,
                                              z_pad, zpart);
  k_conv<<<dim3(512), dim3(256), 0, stream>>>(z_pad, Wfrag, zpart, am_wT, am_b,
                                              owT0, cbias, out);
}